// Round 2
// baseline (3749.722 us; speedup 1.0000x reference)
//
#include <hip/hip_runtime.h>
#include <hip/hip_bf16.h>
#include <cstdint>
#include <cstddef>

typedef __attribute__((ext_vector_type(8))) short bf16x8;
typedef __attribute__((ext_vector_type(4))) float f32x4;
typedef unsigned short u16;

__device__ __forceinline__ u16 f2bf(float f) {
    unsigned int u = __float_as_uint(f);
    u += 0x7fffu + ((u >> 16) & 1u);   // RNE
    return (u16)(u >> 16);
}

__device__ __forceinline__ void gload16(const void* g, void* l) {
    __builtin_amdgcn_global_load_lds((const __attribute__((address_space(1))) void*)g,
                                     (__attribute__((address_space(3))) void*)l,
                                     16, 0, 0);
}

// ---------------- f32 -> bf16 convert (vectorized, exact-fit grid) -------------
__global__ void cvt_f32_bf16(const float* __restrict__ in, u16* __restrict__ out, int n4) {
    int i = blockIdx.x * blockDim.x + threadIdx.x;
    if (i < n4) {
        float4 v = ((const float4*)in)[i];
        ushort4 o;
        o.x = f2bf(v.x); o.y = f2bf(v.y); o.z = f2bf(v.z); o.w = f2bf(v.w);
        ((ushort4*)out)[i] = o;
    }
}

// ---------------- fused expert GEMM layer, V2 --------------------------------
// out[b,n] = act( sum_e gate[b,e] * ( sum_k A[b,k]*Bw[e,n,k] + bias[e,n] ) )
// kt-outer / e-inner: A-tile staged once per kt, af frags held across experts.
// B double-buffered across experts. Fold per (e,kt) as f32x4 FMA with
// transposed-gate broadcast reads.
template<bool ELU_ACT, bool OUT_BF16>
__global__ __launch_bounds__(256, 2)
void moe_layer(const u16* __restrict__ A,
               const u16* __restrict__ Bw,
               const float* __restrict__ gate,
               const float* __restrict__ bias,
               void* __restrict__ outp,
               int N, int K) {
    constexpr int BM = 128, BN = 128, BK = 64, NE = 8;
    __shared__ u16 As[BM * BK];        // 16 KB (swizzled 128B rows)
    __shared__ u16 Bs[2][BN * BK];     // 32 KB double-buffered
    __shared__ float WsT[NE * BM];     // 4 KB gates, TRANSPOSED [e][row]
    __shared__ float BiasS[NE * BN];   // 4 KB

    const int tid  = threadIdx.x;
    const int lane = tid & 63;
    const int wave = tid >> 6;
    const int wr = wave >> 1, wc = wave & 1;
    const int fr = lane & 15;      // row/col within 16x16 frag
    const int fg = lane >> 4;      // k-group (in), row-group (C/D)
    const int m0 = blockIdx.y * BM;
    const int n0 = blockIdx.x * BN;

    // stage gates (transposed) + bias tile
    {
        const int j = tid * 4;
        const int r = j >> 3, e0 = j & 7;
        float4 g = *(const float4*)&gate[(size_t)(m0 + r) * NE + e0];
        WsT[(e0 + 0) * BM + r] = g.x;
        WsT[(e0 + 1) * BM + r] = g.y;
        WsT[(e0 + 2) * BM + r] = g.z;
        WsT[(e0 + 3) * BM + r] = g.w;
        *(float4*)&BiasS[j] = *(const float4*)&bias[(size_t)(j >> 7) * N + n0 + (j & 127)];
    }

    // precompute per-thread staging offsets (kt/e invariant)
    int rowoff[4];   // row*(K*2) + inverse-swizzled col byte
    int ldsoff[4];   // linear LDS chunk byte
    #pragma unroll
    for (int it = 0; it < 4; ++it) {
        const int c   = it * 4 + wave;
        const int L   = c * 1024 + lane * 16;
        const int row = L >> 7;
        const int cb  = (L & 127) ^ ((row & 7) << 4);
        rowoff[it] = row * (K * 2) + cb;
        ldsoff[it] = c * 1024;
    }

    const char* Abase = (const char*)(A + (size_t)m0 * K);
    const char* Bbase0 = (const char*)(Bw + (size_t)n0 * K);
    const size_t Bestride = (size_t)N * K * 2;   // bytes per expert

    const int swz = (fr & 7) << 4;
    const int nkt = K / BK;

    f32x4 tot[4][4];
    const f32x4 zero4 = {0.f, 0.f, 0.f, 0.f};
    #pragma unroll
    for (int a = 0; a < 4; ++a)
        #pragma unroll
        for (int b = 0; b < 4; ++b) tot[a][b] = zero4;

    // prologue: A(kt=0) and B(e=0,kt=0) -> Bs[0]
    #pragma unroll
    for (int it = 0; it < 4; ++it) {
        gload16(Abase + rowoff[it], (char*)As + ldsoff[it]);
        gload16(Bbase0 + rowoff[it], (char*)Bs[0] + ldsoff[it]);
    }
    __syncthreads();

    for (int kt = 0; kt < nkt; ++kt) {
        const int kB = kt * (BK * 2);
        // A fragments for this k-tile, held across all experts
        bf16x8 af[2][4];
        #pragma unroll
        for (int kk = 0; kk < 2; ++kk) {
            const int kb = kk * 64 + fg * 16;
            #pragma unroll
            for (int mi = 0; mi < 4; ++mi) {
                const int r = wr * 64 + mi * 16 + fr;
                af[kk][mi] = *(const bf16x8*)((const char*)As + r * 128 + (kb ^ swz));
            }
        }

        #pragma unroll
        for (int e = 0; e < NE; ++e) {
            // stage next buffer while computing this one
            if (e < NE - 1) {
                const char* Bb = Bbase0 + (size_t)(e + 1) * Bestride;
                #pragma unroll
                for (int it = 0; it < 4; ++it)
                    gload16(Bb + rowoff[it] + kB, (char*)Bs[(e + 1) & 1] + ldsoff[it]);
            } else if (kt + 1 < nkt) {
                const int kB2 = kB + BK * 2;
                #pragma unroll
                for (int it = 0; it < 4; ++it) {
                    gload16(Abase + rowoff[it] + kB2, (char*)As + ldsoff[it]);
                    gload16(Bbase0 + rowoff[it] + kB2, (char*)Bs[0] + ldsoff[it]);
                }
            }

            // B fragments for expert e
            bf16x8 bfr[2][4];
            #pragma unroll
            for (int kk = 0; kk < 2; ++kk) {
                const int kb = kk * 64 + fg * 16;
                #pragma unroll
                for (int ni = 0; ni < 4; ++ni) {
                    const int cc = wc * 64 + ni * 16 + fr;
                    bfr[kk][ni] = *(const bf16x8*)((const char*)Bs[e & 1] + cc * 128 + (kb ^ swz));
                }
            }

            // 32 MFMAs, zero-C on first kk (no accumulator re-zero cost)
            f32x4 acc[4][4];
            #pragma unroll
            for (int mi = 0; mi < 4; ++mi)
                #pragma unroll
                for (int ni = 0; ni < 4; ++ni)
                    acc[mi][ni] = __builtin_amdgcn_mfma_f32_16x16x32_bf16(
                        af[0][mi], bfr[0][ni], zero4, 0, 0, 0);
            #pragma unroll
            for (int mi = 0; mi < 4; ++mi)
                #pragma unroll
                for (int ni = 0; ni < 4; ++ni)
                    acc[mi][ni] = __builtin_amdgcn_mfma_f32_16x16x32_bf16(
                        af[1][mi], bfr[1][ni], acc[mi][ni], 0, 0, 0);

            // fold expert partial into total (vector FMA, broadcast gate reads)
            #pragma unroll
            for (int mi = 0; mi < 4; ++mi) {
                const f32x4 w4 = *(const f32x4*)&WsT[e * BM + wr * 64 + mi * 16 + fg * 4];
                #pragma unroll
                for (int ni = 0; ni < 4; ++ni)
                    tot[mi][ni] += w4 * acc[mi][ni];
            }

            __syncthreads();
        }
    }

    // epilogue: gate-weighted bias, activation, store
    float bias8[4][8];
    #pragma unroll
    for (int ni = 0; ni < 4; ++ni)
        #pragma unroll
        for (int e = 0; e < 8; ++e)
            bias8[ni][e] = BiasS[e * BN + wc * 64 + ni * 16 + fr];

    #pragma unroll
    for (int mi = 0; mi < 4; ++mi) {
        #pragma unroll
        for (int j = 0; j < 4; ++j) {
            const int r = wr * 64 + mi * 16 + fg * 4 + j;
            float g8[8];
            #pragma unroll
            for (int e = 0; e < 8; ++e) g8[e] = WsT[e * BM + r];
            #pragma unroll
            for (int ni = 0; ni < 4; ++ni) {
                float v = tot[mi][ni][j];
                #pragma unroll
                for (int e = 0; e < 8; ++e) v += g8[e] * bias8[ni][e];
                if (ELU_ACT) v = (v > 0.f) ? v : expm1f(v);
                const int cl = wc * 64 + ni * 16 + fr;
                const size_t off = (size_t)(m0 + r) * N + n0 + cl;
                if (OUT_BF16) ((u16*)outp)[off]  = f2bf(v);
                else          ((float*)outp)[off] = v;
            }
        }
    }
}

// ---------------- launcher ----------------------------------------------------
extern "C" void kernel_launch(void* const* d_in, const int* in_sizes, int n_in,
                              void* d_out, int out_size, void* d_ws, size_t ws_size,
                              hipStream_t stream) {
    const float* X  = (const float*)d_in[0];   // [8192,512]
    const float* W  = (const float*)d_in[1];   // [8192,8]
    const float* W1 = (const float*)d_in[2];   // [8,1024,512]
    const float* b1 = (const float*)d_in[3];   // [8,1024]
    const float* W2 = (const float*)d_in[4];   // [8,1024,1024]
    const float* b2 = (const float*)d_in[5];   // [8,1024]
    const float* W3 = (const float*)d_in[6];   // [8,512,1024]
    const float* b3 = (const float*)d_in[7];   // [8,512]
    float* out = (float*)d_out;

    char* ws = (char*)d_ws;
    u16* Xb   = (u16*)ws;  ws += (size_t)8192 * 512 * 2;
    u16* W1b  = (u16*)ws;  ws += (size_t)8 * 1024 * 512 * 2;
    u16* W2b  = (u16*)ws;  ws += (size_t)8 * 1024 * 1024 * 2;
    u16* W3b  = (u16*)ws;  ws += (size_t)8 * 512 * 1024 * 2;
    u16* mid1 = (u16*)ws;  ws += (size_t)8192 * 1024 * 2;
    u16* mid2 = (u16*)ws;  ws += (size_t)8192 * 1024 * 2;

    cvt_f32_bf16<<<4096, 256, 0, stream>>>(X,  Xb,  4194304 / 4);
    cvt_f32_bf16<<<4096, 256, 0, stream>>>(W1, W1b, 4194304 / 4);
    cvt_f32_bf16<<<8192, 256, 0, stream>>>(W2, W2b, 8388608 / 4);
    cvt_f32_bf16<<<4096, 256, 0, stream>>>(W3, W3b, 4194304 / 4);

    dim3 blk(256);
    // L1: A=Xb [8192,512], Bw=W1b [8,1024,512] -> mid1 (ELU, bf16)
    moe_layer<true, true><<<dim3(1024 / 128, 8192 / 128), blk, 0, stream>>>(
        Xb, W1b, W, b1, (void*)mid1, 1024, 512);
    // L2: A=mid1, Bw=W2b [8,1024,1024] -> mid2 (ELU, bf16)
    moe_layer<true, true><<<dim3(1024 / 128, 8192 / 128), blk, 0, stream>>>(
        mid1, W2b, W, b2, (void*)mid2, 1024, 1024);
    // L3: A=mid2, Bw=W3b [8,512,1024] -> out (no act, f32)
    moe_layer<false, false><<<dim3(512 / 128, 8192 / 128), blk, 0, stream>>>(
        mid2, W3b, W, b3, (void*)out, 512, 1024);
}

// Round 3
// 551.279 us; speedup vs baseline: 6.8019x; 6.8019x over previous
//
#include <hip/hip_runtime.h>
#include <hip/hip_bf16.h>
#include <cstdint>
#include <cstddef>

typedef __attribute__((ext_vector_type(8))) short bf16x8;
typedef __attribute__((ext_vector_type(8))) unsigned short u16x8;
typedef __attribute__((ext_vector_type(4))) float f32x4;
typedef unsigned short u16;

__device__ __forceinline__ u16 f2bf(float f) {
    unsigned int u = __float_as_uint(f);
    u += 0x7fffu + ((u >> 16) & 1u);   // RNE
    return (u16)(u >> 16);
}
__device__ __forceinline__ float bf2f(u16 u) {
    return __uint_as_float(((unsigned int)u) << 16);
}

__device__ __forceinline__ void gload16(const void* g, void* l) {
    __builtin_amdgcn_global_load_lds((const __attribute__((address_space(1))) void*)g,
                                     (__attribute__((address_space(3))) void*)l,
                                     16, 0, 0);
}

// ---------------- f32 -> bf16 convert (weights) -------------------------------
__global__ void cvt_f32_bf16(const float* __restrict__ in, u16* __restrict__ out, int n4) {
    int i = blockIdx.x * blockDim.x + threadIdx.x;
    if (i < n4) {
        float4 v = ((const float4*)in)[i];
        ushort4 o;
        o.x = f2bf(v.x); o.y = f2bf(v.y); o.z = f2bf(v.z); o.w = f2bf(v.w);
        ((ushort4*)out)[i] = o;
    }
}

// ---------------- gated-A materialization: At[b, e*K+k] = g[b,e]*A[b,k] -------
__global__ void make_atilde_f32(const float* __restrict__ A, const float* __restrict__ gate,
                                u16* __restrict__ out, int log2K) {
    const size_t idx = ((size_t)blockIdx.x * 256 + threadIdx.x) * 8;
    const int K = 1 << log2K;
    const size_t b = idx >> (log2K + 3);
    const int rem = (int)(idx - (b << (log2K + 3)));
    const int e = rem >> log2K;
    const int k = rem & (K - 1);
    const float g = gate[b * 8 + e];
    const float* src = A + b * (size_t)K + k;
    float4 v0 = ((const float4*)src)[0];
    float4 v1 = ((const float4*)src)[1];
    u16x8 r;
    r[0] = f2bf(g * v0.x); r[1] = f2bf(g * v0.y); r[2] = f2bf(g * v0.z); r[3] = f2bf(g * v0.w);
    r[4] = f2bf(g * v1.x); r[5] = f2bf(g * v1.y); r[6] = f2bf(g * v1.z); r[7] = f2bf(g * v1.w);
    *(u16x8*)(out + idx) = r;
}

__global__ void make_atilde_bf16(const u16* __restrict__ A, const float* __restrict__ gate,
                                 u16* __restrict__ out, int log2K) {
    const size_t idx = ((size_t)blockIdx.x * 256 + threadIdx.x) * 8;
    const int K = 1 << log2K;
    const size_t b = idx >> (log2K + 3);
    const int rem = (int)(idx - (b << (log2K + 3)));
    const int e = rem >> log2K;
    const int k = rem & (K - 1);
    const float g = gate[b * 8 + e];
    u16x8 a = *(const u16x8*)(A + b * (size_t)K + k);
    u16x8 r;
    #pragma unroll
    for (int j = 0; j < 8; ++j) r[j] = f2bf(g * bf2f(a[j]));
    *(u16x8*)(out + idx) = r;
}

// ---------------- standard big-K GEMM over gated-A -----------------------------
// out[b,n] = act( sum_{kt} At[b,:]·Bw-slice + sum_e gate[b,e]*bias[e,n] )
// At: [M, Ktot] bf16 row-major (Ktot = 8*K). Bw: [8, N, K] bf16 (B^T per expert).
// Tile 128x128, BK=64, 256 threads (4 waves 2x2), m97-style 2-barrier loop.
template<bool ELU_ACT, bool OUT_BF16>
__global__ void moe_gemm(const u16* __restrict__ At,
                         const u16* __restrict__ Bw,
                         const float* __restrict__ gate,
                         const float* __restrict__ bias,
                         void* __restrict__ outp,
                         int N, int K, int Ktot, int log2nk,
                         int rows_per_xcd, int bxbits) {
    constexpr int BM = 128, BN = 128, BK = 64, NE = 8;
    __shared__ u16 As[BM * BK];        // 16 KB, swizzled 128B rows
    __shared__ u16 Bs[BN * BK];        // 16 KB
    __shared__ float Ws[BM * NE];      // 4 KB  gates [row][e] (epilogue only)
    __shared__ float BiasS[NE * BN];   // 4 KB

    const int tid  = threadIdx.x;
    const int lane = tid & 63;
    const int wave = tid >> 6;
    const int wr = wave >> 1, wc = wave & 1;
    const int fr = lane & 15;
    const int fg = lane >> 4;

    // XCD m-chunked swizzle: co-locate blocks sharing an A row-panel
    const int bid = blockIdx.x;
    const int xcd = bid & 7, idx = bid >> 3;
    const int by = xcd * rows_per_xcd + (idx >> bxbits);
    const int bx = idx & ((1 << bxbits) - 1);
    const int m0 = by * BM;
    const int n0 = bx * BN;

    // stage gates + bias tile (epilogue data)
    {
        const int j = tid * 4;
        *(float4*)&Ws[j]    = *(const float4*)&gate[(size_t)(m0 + (j >> 3)) * NE + (j & 7)];
        *(float4*)&BiasS[j] = *(const float4*)&bias[(size_t)(j >> 7) * N + n0 + (j & 127)];
    }

    // per-thread staging offsets (kt-invariant)
    int rowoffA[4], rowoffB[4], ldsoff[4];
    #pragma unroll
    for (int it = 0; it < 4; ++it) {
        const int c   = it * 4 + wave;
        const int L   = c * 1024 + lane * 16;
        const int row = L >> 7;
        const int cb  = (L & 127) ^ ((row & 7) << 4);  // inverse-swizzled src col
        rowoffA[it] = row * (Ktot * 2) + cb;
        rowoffB[it] = row * (K * 2) + cb;
        ldsoff[it]  = c * 1024;
    }

    const char* Abase = (const char*)(At + (size_t)m0 * Ktot);
    const char* Bbase = (const char*)(Bw + (size_t)n0 * K);
    const size_t Bestride = (size_t)N * K * 2;
    const int swz  = (fr & 7) << 4;
    const int nkt  = Ktot / BK;
    const int nkmask = (1 << log2nk) - 1;

    f32x4 acc[4][4];
    #pragma unroll
    for (int a = 0; a < 4; ++a)
        #pragma unroll
        for (int b = 0; b < 4; ++b) acc[a][b] = f32x4{0.f, 0.f, 0.f, 0.f};

    for (int kt = 0; kt < nkt; ++kt) {
        __syncthreads();   // previous tile's LDS reads done
        const char* Ab = Abase + kt * 128;
        const char* Bb = Bbase + (size_t)(kt >> log2nk) * Bestride + (kt & nkmask) * 128;
        #pragma unroll
        for (int it = 0; it < 4; ++it) {
            gload16(Ab + rowoffA[it], (char*)As + ldsoff[it]);
            gload16(Bb + rowoffB[it], (char*)Bs + ldsoff[it]);
        }
        __syncthreads();   // staged data visible

        #pragma unroll
        for (int kk = 0; kk < 2; ++kk) {
            const int kb = kk * 64 + fg * 16;
            bf16x8 af[4], bfr[4];
            #pragma unroll
            for (int mi = 0; mi < 4; ++mi) {
                const int r  = wr * 64 + mi * 16 + fr;
                af[mi]  = *(const bf16x8*)((const char*)As + r * 128 + (kb ^ swz));
                const int cc = wc * 64 + mi * 16 + fr;
                bfr[mi] = *(const bf16x8*)((const char*)Bs + cc * 128 + (kb ^ swz));
            }
            #pragma unroll
            for (int mi = 0; mi < 4; ++mi)
                #pragma unroll
                for (int ni = 0; ni < 4; ++ni)
                    acc[mi][ni] = __builtin_amdgcn_mfma_f32_16x16x32_bf16(
                        af[mi], bfr[ni], acc[mi][ni], 0, 0, 0);
        }
    }

    // epilogue: gate-weighted bias, activation, store
    float bias8[4][8];
    #pragma unroll
    for (int ni = 0; ni < 4; ++ni)
        #pragma unroll
        for (int e = 0; e < 8; ++e)
            bias8[ni][e] = BiasS[e * BN + wc * 64 + ni * 16 + fr];

    #pragma unroll
    for (int mi = 0; mi < 4; ++mi) {
        #pragma unroll
        for (int j = 0; j < 4; ++j) {
            const int r = wr * 64 + mi * 16 + fg * 4 + j;
            float g8[8];
            #pragma unroll
            for (int e = 0; e < 8; ++e) g8[e] = Ws[r * NE + e];
            #pragma unroll
            for (int ni = 0; ni < 4; ++ni) {
                float v = acc[mi][ni][j];
                #pragma unroll
                for (int e = 0; e < 8; ++e) v += g8[e] * bias8[ni][e];
                if (ELU_ACT) v = (v > 0.f) ? v : expm1f(v);
                const int cl = wc * 64 + ni * 16 + fr;
                const size_t off = (size_t)(m0 + r) * N + n0 + cl;
                if (OUT_BF16) ((u16*)outp)[off]  = f2bf(v);
                else          ((float*)outp)[off] = v;
            }
        }
    }
}

// ---------------- launcher ----------------------------------------------------
extern "C" void kernel_launch(void* const* d_in, const int* in_sizes, int n_in,
                              void* d_out, int out_size, void* d_ws, size_t ws_size,
                              hipStream_t stream) {
    const float* X  = (const float*)d_in[0];   // [8192,512]
    const float* W  = (const float*)d_in[1];   // [8192,8]
    const float* W1 = (const float*)d_in[2];   // [8,1024,512]
    const float* b1 = (const float*)d_in[3];   // [8,1024]
    const float* W2 = (const float*)d_in[4];   // [8,1024,1024]
    const float* b2 = (const float*)d_in[5];   // [8,1024]
    const float* W3 = (const float*)d_in[6];   // [8,512,1024]
    const float* b3 = (const float*)d_in[7];   // [8,512]
    float* out = (float*)d_out;

    char* ws = (char*)d_ws;
    u16* W1b  = (u16*)ws;  ws += (size_t)8 * 1024 * 512 * 2;     //  8.4 MB
    u16* W2b  = (u16*)ws;  ws += (size_t)8 * 1024 * 1024 * 2;    // 16.8 MB
    u16* W3b  = (u16*)ws;  ws += (size_t)8 * 512 * 1024 * 2;     //  8.4 MB
    u16* mid1 = (u16*)ws;  ws += (size_t)8192 * 1024 * 2;        // 16.8 MB
    u16* mid2 = (u16*)ws;  ws += (size_t)8192 * 1024 * 2;        // 16.8 MB
    u16* At1  = (u16*)ws;  ws += (size_t)8192 * 4096 * 2;        //   67 MB
    u16* At2  = (u16*)ws;  ws += (size_t)8192 * 8192 * 2;        //  134 MB (reused for At3)

    // weight converts
    cvt_f32_bf16<<<4096, 256, 0, stream>>>(W1, W1b, 4194304 / 4);
    cvt_f32_bf16<<<8192, 256, 0, stream>>>(W2, W2b, 8388608 / 4);
    cvt_f32_bf16<<<4096, 256, 0, stream>>>(W3, W3b, 4194304 / 4);

    dim3 blk(256);

    // L1: At1 = gate ⊙ X  [8192, 4096];  GEMM -> mid1 (ELU, bf16)
    make_atilde_f32<<<16384, blk, 0, stream>>>(X, W, At1, 9);
    moe_gemm<true, true><<<512, blk, 0, stream>>>(
        At1, W1b, W, b1, (void*)mid1, 1024, 512, 4096, 3, 8, 3);

    // L2: At2 = gate ⊙ mid1 [8192, 8192]; GEMM -> mid2 (ELU, bf16)
    make_atilde_bf16<<<32768, blk, 0, stream>>>(mid1, W, At2, 10);
    moe_gemm<true, true><<<512, blk, 0, stream>>>(
        At2, W2b, W, b2, (void*)mid2, 1024, 1024, 8192, 4, 8, 3);

    // L3: At3 = gate ⊙ mid2 [8192, 8192] (reuse At2); GEMM -> out (f32)
    make_atilde_bf16<<<32768, blk, 0, stream>>>(mid2, W, At2, 10);
    moe_gemm<false, false><<<256, blk, 0, stream>>>(
        At2, W3b, W, b3, (void*)out, 512, 1024, 8192, 4, 8, 2);
}

// Round 4
// 507.993 us; speedup vs baseline: 7.3814x; 1.0852x over previous
//
#include <hip/hip_runtime.h>
#include <hip/hip_bf16.h>
#include <cstdint>
#include <cstddef>

typedef __attribute__((ext_vector_type(8))) short bf16x8;
typedef __attribute__((ext_vector_type(8))) unsigned short u16x8;
typedef __attribute__((ext_vector_type(4))) float f32x4;
typedef unsigned short u16;

__device__ __forceinline__ u16 f2bf(float f) {
    unsigned int u = __float_as_uint(f);
    u += 0x7fffu + ((u >> 16) & 1u);   // RNE
    return (u16)(u >> 16);
}
__device__ __forceinline__ float bf2f(u16 u) {
    return __uint_as_float(((unsigned int)u) << 16);
}

__device__ __forceinline__ void gload16(const void* g, void* l) {
    __builtin_amdgcn_global_load_lds((const __attribute__((address_space(1))) void*)g,
                                     (__attribute__((address_space(3))) void*)l,
                                     16, 0, 0);
}

// ---------------- f32 -> bf16 convert (weights) -------------------------------
__global__ void cvt_f32_bf16(const float* __restrict__ in, u16* __restrict__ out, int n4) {
    int i = blockIdx.x * blockDim.x + threadIdx.x;
    if (i < n4) {
        float4 v = ((const float4*)in)[i];
        ushort4 o;
        o.x = f2bf(v.x); o.y = f2bf(v.y); o.z = f2bf(v.z); o.w = f2bf(v.w);
        ((ushort4*)out)[i] = o;
    }
}

// ---------------- gated-A materialization: At[b, e*K+k] = g[b,e]*A[b,k] -------
__global__ void make_atilde_f32(const float* __restrict__ A, const float* __restrict__ gate,
                                u16* __restrict__ out, int log2K) {
    const size_t idx = ((size_t)blockIdx.x * 256 + threadIdx.x) * 8;
    const int K = 1 << log2K;
    const size_t b = idx >> (log2K + 3);
    const int rem = (int)(idx - (b << (log2K + 3)));
    const int e = rem >> log2K;
    const int k = rem & (K - 1);
    const float g = gate[b * 8 + e];
    const float* src = A + b * (size_t)K + k;
    float4 v0 = ((const float4*)src)[0];
    float4 v1 = ((const float4*)src)[1];
    u16x8 r;
    r[0] = f2bf(g * v0.x); r[1] = f2bf(g * v0.y); r[2] = f2bf(g * v0.z); r[3] = f2bf(g * v0.w);
    r[4] = f2bf(g * v1.x); r[5] = f2bf(g * v1.y); r[6] = f2bf(g * v1.z); r[7] = f2bf(g * v1.w);
    *(u16x8*)(out + idx) = r;
}

__global__ void make_atilde_bf16(const u16* __restrict__ A, const float* __restrict__ gate,
                                 u16* __restrict__ out, int log2K) {
    const size_t idx = ((size_t)blockIdx.x * 256 + threadIdx.x) * 8;
    const int K = 1 << log2K;
    const size_t b = idx >> (log2K + 3);
    const int rem = (int)(idx - (b << (log2K + 3)));
    const int e = rem >> log2K;
    const int k = rem & (K - 1);
    const float g = gate[b * 8 + e];
    u16x8 a = *(const u16x8*)(A + b * (size_t)K + k);
    u16x8 r;
    #pragma unroll
    for (int j = 0; j < 8; ++j) r[j] = f2bf(g * bf2f(a[j]));
    *(u16x8*)(out + idx) = r;
}

// ---------------- standard big-K GEMM over gated-A, 2-phase prefetch ----------
// out[b,n] = act( sum_kt At-slice · Bw-slice + sum_e gate[b,e]*bias[e,n] )
// At: [M, Ktot] bf16 row-major (Ktot = 8*K). Bw: [8, N, K] bf16 (B^T per expert).
// Tile 128xBN, BK=64, 256 threads (4 waves 2x2), double-buffered LDS,
// stage(next) issued BEFORE compute(cur), ONE barrier per k-tile.
template<bool ELU_ACT, bool OUT_BF16, int BN>
__global__ void moe_gemm(const u16* __restrict__ At,
                         const u16* __restrict__ Bw,
                         const float* __restrict__ gate,
                         const float* __restrict__ bias,
                         void* __restrict__ outp,
                         int N, int K, int Ktot, int log2nk,
                         int rows_per_xcd, int bxbits) {
    constexpr int BM = 128, BK = 64, NE = 8;
    constexpr int NI = BN / 32;          // 16-wide C frags per wave in n
    constexpr int NB_IT = BN / 32;       // B staging iterations (BN/8 chunks / 4 waves)
    __shared__ u16 As[2][BM * BK];       // 2x16 KB, swizzled 128B rows
    __shared__ u16 Bs[2][BN * BK];       // 2x(16|8) KB
    __shared__ float Ws[BM * NE];        // 4 KB gates (epilogue)
    __shared__ float BiasS[NE * BN];     // 4|2 KB

    const int tid  = threadIdx.x;
    const int lane = tid & 63;
    const int wave = tid >> 6;
    const int wr = wave >> 1, wc = wave & 1;
    const int fr = lane & 15;
    const int fg = lane >> 4;

    // XCD m-chunked swizzle
    const int bid = blockIdx.x;
    const int xcd = bid & 7, idx = bid >> 3;
    const int by = xcd * rows_per_xcd + (idx >> bxbits);
    const int bx = idx & ((1 << bxbits) - 1);
    const int m0 = by * BM;
    const int n0 = bx * BN;

    // stage gates + bias tile (epilogue data)
    {
        const int j = tid * 4;
        *(float4*)&Ws[j] = *(const float4*)&gate[(size_t)(m0 + (j >> 3)) * NE + (j & 7)];
        if (j < NE * BN)
            *(float4*)&BiasS[j] = *(const float4*)&bias[(size_t)(j / BN) * N + n0 + (j & (BN - 1))];
    }

    // per-thread staging offsets (kt-invariant)
    int rowoffA[4], ldsA[4], rowoffB[NB_IT], ldsB[NB_IT];
    #pragma unroll
    for (int it = 0; it < 4; ++it) {
        const int c   = it * 4 + wave;
        const int L   = c * 1024 + lane * 16;
        const int row = L >> 7;
        const int cb  = (L & 127) ^ ((row & 7) << 4);
        rowoffA[it] = row * (Ktot * 2) + cb;
        ldsA[it]    = c * 1024;
    }
    #pragma unroll
    for (int it = 0; it < NB_IT; ++it) {
        const int c   = it * 4 + wave;
        const int L   = c * 1024 + lane * 16;
        const int row = L >> 7;
        const int cb  = (L & 127) ^ ((row & 7) << 4);
        rowoffB[it] = row * (K * 2) + cb;
        ldsB[it]    = c * 1024;
    }

    const char* Abase = (const char*)(At + (size_t)m0 * Ktot);
    const char* Bbase = (const char*)(Bw + (size_t)n0 * K);
    const size_t Bestride = (size_t)N * K * 2;
    const int swz  = (fr & 7) << 4;
    const int nkt  = Ktot / BK;
    const int nkmask = (1 << log2nk) - 1;

    f32x4 acc[4][NI];
    #pragma unroll
    for (int a = 0; a < 4; ++a)
        #pragma unroll
        for (int b = 0; b < NI; ++b) acc[a][b] = f32x4{0.f, 0.f, 0.f, 0.f};

    // prologue: stage tile 0 into buffer 0
    {
        #pragma unroll
        for (int it = 0; it < 4; ++it)
            gload16(Abase + rowoffA[it], (char*)As[0] + ldsA[it]);
        #pragma unroll
        for (int it = 0; it < NB_IT; ++it)
            gload16(Bbase + rowoffB[it], (char*)Bs[0] + ldsB[it]);
    }
    __syncthreads();

    for (int kt = 0; kt < nkt; ++kt) {
        const int cur = kt & 1;
        // issue next tile's loads into the other buffer (prefetch)
        if (kt + 1 < nkt) {
            const int kn = kt + 1;
            const char* Ab = Abase + kn * 128;
            const char* Bb = Bbase + (size_t)(kn >> log2nk) * Bestride + (kn & nkmask) * 128;
            #pragma unroll
            for (int it = 0; it < 4; ++it)
                gload16(Ab + rowoffA[it], (char*)As[cur ^ 1] + ldsA[it]);
            #pragma unroll
            for (int it = 0; it < NB_IT; ++it)
                gload16(Bb + rowoffB[it], (char*)Bs[cur ^ 1] + ldsB[it]);
        }

        // compute current buffer
        const char* Ac = (const char*)As[cur];
        const char* Bc = (const char*)Bs[cur];
        #pragma unroll
        for (int kk = 0; kk < 2; ++kk) {
            const int kb = kk * 64 + fg * 16;
            bf16x8 af[4], bfr[NI];
            #pragma unroll
            for (int mi = 0; mi < 4; ++mi) {
                const int r = wr * 64 + mi * 16 + fr;
                af[mi] = *(const bf16x8*)(Ac + r * 128 + (kb ^ swz));
            }
            #pragma unroll
            for (int ni = 0; ni < NI; ++ni) {
                const int cc = wc * (BN / 2) + ni * 16 + fr;
                bfr[ni] = *(const bf16x8*)(Bc + cc * 128 + (kb ^ swz));
            }
            #pragma unroll
            for (int mi = 0; mi < 4; ++mi)
                #pragma unroll
                for (int ni = 0; ni < NI; ++ni)
                    acc[mi][ni] = __builtin_amdgcn_mfma_f32_16x16x32_bf16(
                        af[mi], bfr[ni], acc[mi][ni], 0, 0, 0);
        }

        // one barrier per k-tile: drains this wave's prefetch loads (vmcnt 0
        // emitted by compiler before s_barrier) AND protects buffer reuse.
        __syncthreads();
    }

    // epilogue: gate-weighted bias, activation, store
    float bias8[NI][8];
    #pragma unroll
    for (int ni = 0; ni < NI; ++ni)
        #pragma unroll
        for (int e = 0; e < 8; ++e)
            bias8[ni][e] = BiasS[e * BN + wc * (BN / 2) + ni * 16 + fr];

    #pragma unroll
    for (int mi = 0; mi < 4; ++mi) {
        #pragma unroll
        for (int j = 0; j < 4; ++j) {
            const int r = wr * 64 + mi * 16 + fg * 4 + j;
            float g8[8];
            #pragma unroll
            for (int e = 0; e < 8; ++e) g8[e] = Ws[r * NE + e];
            #pragma unroll
            for (int ni = 0; ni < NI; ++ni) {
                float v = acc[mi][ni][j];
                #pragma unroll
                for (int e = 0; e < 8; ++e) v += g8[e] * bias8[ni][e];
                if (ELU_ACT) v = (v > 0.f) ? v : expm1f(v);
                const int cl = wc * (BN / 2) + ni * 16 + fr;
                const size_t off = (size_t)(m0 + r) * N + n0 + cl;
                if (OUT_BF16) ((u16*)outp)[off]  = f2bf(v);
                else          ((float*)outp)[off] = v;
            }
        }
    }
}

// ---------------- launcher ----------------------------------------------------
extern "C" void kernel_launch(void* const* d_in, const int* in_sizes, int n_in,
                              void* d_out, int out_size, void* d_ws, size_t ws_size,
                              hipStream_t stream) {
    const float* X  = (const float*)d_in[0];   // [8192,512]
    const float* W  = (const float*)d_in[1];   // [8192,8]
    const float* W1 = (const float*)d_in[2];   // [8,1024,512]
    const float* b1 = (const float*)d_in[3];   // [8,1024]
    const float* W2 = (const float*)d_in[4];   // [8,1024,1024]
    const float* b2 = (const float*)d_in[5];   // [8,1024]
    const float* W3 = (const float*)d_in[6];   // [8,512,1024]
    const float* b3 = (const float*)d_in[7];   // [8,512]
    float* out = (float*)d_out;

    char* ws = (char*)d_ws;
    u16* W1b  = (u16*)ws;  ws += (size_t)8 * 1024 * 512 * 2;     //  8.4 MB
    u16* W2b  = (u16*)ws;  ws += (size_t)8 * 1024 * 1024 * 2;    // 16.8 MB
    u16* W3b  = (u16*)ws;  ws += (size_t)8 * 512 * 1024 * 2;     //  8.4 MB
    u16* mid1 = (u16*)ws;  ws += (size_t)8192 * 1024 * 2;        // 16.8 MB
    u16* mid2 = (u16*)ws;  ws += (size_t)8192 * 1024 * 2;        // 16.8 MB
    u16* At1  = (u16*)ws;  ws += (size_t)8192 * 4096 * 2;        //   67 MB
    u16* At2  = (u16*)ws;  ws += (size_t)8192 * 8192 * 2;        //  134 MB (reused for At3)

    // weight converts
    cvt_f32_bf16<<<4096, 256, 0, stream>>>(W1, W1b, 4194304 / 4);
    cvt_f32_bf16<<<8192, 256, 0, stream>>>(W2, W2b, 8388608 / 4);
    cvt_f32_bf16<<<4096, 256, 0, stream>>>(W3, W3b, 4194304 / 4);

    dim3 blk(256);

    // L1: At1 = gate ⊙ X  [8192, 4096];  GEMM -> mid1 (ELU, bf16)
    make_atilde_f32<<<16384, blk, 0, stream>>>(X, W, At1, 9);
    moe_gemm<true, true, 128><<<512, blk, 0, stream>>>(
        At1, W1b, W, b1, (void*)mid1, 1024, 512, 4096, 3, 8, 3);

    // L2: At2 = gate ⊙ mid1 [8192, 8192]; GEMM -> mid2 (ELU, bf16)
    make_atilde_bf16<<<32768, blk, 0, stream>>>(mid1, W, At2, 10);
    moe_gemm<true, true, 128><<<512, blk, 0, stream>>>(
        At2, W2b, W, b2, (void*)mid2, 1024, 1024, 8192, 4, 8, 3);

    // L3: At3 = gate ⊙ mid2 [8192, 8192] (reuse At2); GEMM -> out (f32), BN=64
    make_atilde_bf16<<<32768, blk, 0, stream>>>(mid2, W, At2, 10);
    moe_gemm<false, false, 64><<<512, blk, 0, stream>>>(
        At2, W3b, W, b3, (void*)out, 512, 1024, 8192, 4, 8, 3);
}

// Round 5
// 432.192 us; speedup vs baseline: 8.6761x; 1.1754x over previous
//
#include <hip/hip_runtime.h>
#include <hip/hip_bf16.h>
#include <cstdint>
#include <cstddef>

typedef __attribute__((ext_vector_type(8))) short bf16x8;
typedef __attribute__((ext_vector_type(8))) unsigned short u16x8;
typedef __attribute__((ext_vector_type(4))) float f32x4;
typedef unsigned short u16;

__device__ __forceinline__ u16 f2bf(float f) {
    unsigned int u = __float_as_uint(f);
    u += 0x7fffu + ((u >> 16) & 1u);   // RNE
    return (u16)(u >> 16);
}
__device__ __forceinline__ float bf2f(u16 u) {
    return __uint_as_float(((unsigned int)u) << 16);
}

__device__ __forceinline__ void gload16(const void* g, void* l) {
    __builtin_amdgcn_global_load_lds((const __attribute__((address_space(1))) void*)g,
                                     (__attribute__((address_space(3))) void*)l,
                                     16, 0, 0);
}

// ---------------- f32 -> bf16 convert (weights) -------------------------------
__global__ void cvt_f32_bf16(const float* __restrict__ in, u16* __restrict__ out, int n4) {
    int i = blockIdx.x * blockDim.x + threadIdx.x;
    if (i < n4) {
        float4 v = ((const float4*)in)[i];
        ushort4 o;
        o.x = f2bf(v.x); o.y = f2bf(v.y); o.z = f2bf(v.z); o.w = f2bf(v.w);
        ((ushort4*)out)[i] = o;
    }
}

// ---------------- gated-A materialization: At[b, e*K+k] = g[b,e]*A[b,k] -------
__global__ void make_atilde_f32(const float* __restrict__ A, const float* __restrict__ gate,
                                u16* __restrict__ out, int log2K) {
    const size_t idx = ((size_t)blockIdx.x * 256 + threadIdx.x) * 8;
    const int K = 1 << log2K;
    const size_t b = idx >> (log2K + 3);
    const int rem = (int)(idx - (b << (log2K + 3)));
    const int e = rem >> log2K;
    const int k = rem & (K - 1);
    const float g = gate[b * 8 + e];
    const float* src = A + b * (size_t)K + k;
    float4 v0 = ((const float4*)src)[0];
    float4 v1 = ((const float4*)src)[1];
    u16x8 r;
    r[0] = f2bf(g * v0.x); r[1] = f2bf(g * v0.y); r[2] = f2bf(g * v0.z); r[3] = f2bf(g * v0.w);
    r[4] = f2bf(g * v1.x); r[5] = f2bf(g * v1.y); r[6] = f2bf(g * v1.z); r[7] = f2bf(g * v1.w);
    *(u16x8*)(out + idx) = r;
}

__global__ void make_atilde_bf16(const u16* __restrict__ A, const float* __restrict__ gate,
                                 u16* __restrict__ out, int log2K) {
    const size_t idx = ((size_t)blockIdx.x * 256 + threadIdx.x) * 8;
    const int K = 1 << log2K;
    const size_t b = idx >> (log2K + 3);
    const int rem = (int)(idx - (b << (log2K + 3)));
    const int e = rem >> log2K;
    const int k = rem & (K - 1);
    const float g = gate[b * 8 + e];
    u16x8 a = *(const u16x8*)(A + b * (size_t)K + k);
    u16x8 r;
    #pragma unroll
    for (int j = 0; j < 8; ++j) r[j] = f2bf(g * bf2f(a[j]));
    *(u16x8*)(out + idx) = r;
}

// ---------------- split-K GEMM over gated-A (m97 2-barrier, 32KB LDS) ---------
// P[s][b][n] = sum_{kt in segment s} At-slice · Bw-slice   (raw f32 partials)
// At: [M, Ktot] bf16. Bw: [8, N, K] bf16 (B^T per expert). Tile 128x128, BK=64.
__global__ __launch_bounds__(256, 4)
void moe_gemm_sk(const u16* __restrict__ At,
                 const u16* __restrict__ Bw,
                 float* __restrict__ P,
                 int N, int K, int Ktot, int log2nk,
                 int rows_per_xcd, int bxbits, int log2S, int kt_per_s) {
    constexpr int BM = 128, BN = 128, BK = 64;
    __shared__ u16 As[BM * BK];    // 16 KB, swizzled 128B rows
    __shared__ u16 Bs[BN * BK];    // 16 KB

    const int tid  = threadIdx.x;
    const int lane = tid & 63;
    const int wave = tid >> 6;
    const int wr = wave >> 1, wc = wave & 1;
    const int fr = lane & 15;
    const int fg = lane >> 4;

    // decompose: XCD-swizzled (s, by, bx); same-XCD blocks share (s,by) A-panel
    const int bid = blockIdx.x;
    const int xcd = bid & 7, idx = bid >> 3;
    const int bx  = idx & ((1 << bxbits) - 1);
    const int bys = idx >> bxbits;
    const int s   = bys & ((1 << log2S) - 1);
    const int by  = xcd * rows_per_xcd + (bys >> log2S);
    const int m0  = by * BM;
    const int n0  = bx * BN;

    // per-thread staging offsets (kt-invariant)
    int rowoffA[4], rowoffB[4], ldsoff[4];
    #pragma unroll
    for (int it = 0; it < 4; ++it) {
        const int c   = it * 4 + wave;
        const int L   = c * 1024 + lane * 16;
        const int row = L >> 7;
        const int cb  = (L & 127) ^ ((row & 7) << 4);   // inverse-swizzled src col
        rowoffA[it] = row * (Ktot * 2) + cb;
        rowoffB[it] = row * (K * 2) + cb;
        ldsoff[it]  = c * 1024;
    }

    const char* Abase = (const char*)(At + (size_t)m0 * Ktot);
    const char* Bbase = (const char*)(Bw + (size_t)n0 * K);
    const size_t Bestride = (size_t)N * K * 2;
    const int swz    = (fr & 7) << 4;
    const int nkmask = (1 << log2nk) - 1;
    const int kt0    = s * kt_per_s;

    f32x4 acc[4][4];
    #pragma unroll
    for (int a = 0; a < 4; ++a)
        #pragma unroll
        for (int b = 0; b < 4; ++b) acc[a][b] = f32x4{0.f, 0.f, 0.f, 0.f};

    for (int t = 0; t < kt_per_s; ++t) {
        const int kt = kt0 + t;
        __syncthreads();   // previous tile's LDS reads done
        const char* Ab = Abase + kt * 128;
        const char* Bb = Bbase + (size_t)(kt >> log2nk) * Bestride + (kt & nkmask) * 128;
        #pragma unroll
        for (int it = 0; it < 4; ++it) {
            gload16(Ab + rowoffA[it], (char*)As + ldsoff[it]);
            gload16(Bb + rowoffB[it], (char*)Bs + ldsoff[it]);
        }
        __syncthreads();   // staged data visible

        #pragma unroll
        for (int kk = 0; kk < 2; ++kk) {
            const int kb = kk * 64 + fg * 16;
            bf16x8 af[4], bfr[4];
            #pragma unroll
            for (int mi = 0; mi < 4; ++mi) {
                const int r  = wr * 64 + mi * 16 + fr;
                af[mi]  = *(const bf16x8*)((const char*)As + r * 128 + (kb ^ swz));
                const int cc = wc * 64 + mi * 16 + fr;
                bfr[mi] = *(const bf16x8*)((const char*)Bs + cc * 128 + (kb ^ swz));
            }
            #pragma unroll
            for (int mi = 0; mi < 4; ++mi)
                #pragma unroll
                for (int ni = 0; ni < 4; ++ni)
                    acc[mi][ni] = __builtin_amdgcn_mfma_f32_16x16x32_bf16(
                        af[mi], bfr[ni], acc[mi][ni], 0, 0, 0);
        }
    }

    // epilogue: raw f32 partial store
    float* Pb = P + ((size_t)s * 8192 + m0) * N + n0;
    #pragma unroll
    for (int mi = 0; mi < 4; ++mi) {
        #pragma unroll
        for (int j = 0; j < 4; ++j) {
            const int r = wr * 64 + mi * 16 + fg * 4 + j;
            #pragma unroll
            for (int ni = 0; ni < 4; ++ni) {
                const int cl = wc * 64 + ni * 16 + fr;
                Pb[(size_t)r * N + cl] = acc[mi][ni][j];
            }
        }
    }
}

// ---------------- split-K reduce: sum partials + gate-weighted bias + act -----
template<int S, bool ELU_ACT, bool OUT_BF16>
__global__ void moe_reduce(const float* __restrict__ P,
                           const float* __restrict__ gate,
                           const float* __restrict__ bias,
                           void* __restrict__ outp,
                           int log2N, int n4total) {
    const int stride = gridDim.x * blockDim.x;
    const size_t MN = ((size_t)n4total) * 4;
    for (int i = blockIdx.x * blockDim.x + threadIdx.x; i < n4total; i += stride) {
        const size_t el = (size_t)i * 4;
        const size_t b = el >> log2N;
        const int n = (int)(el & ((1 << log2N) - 1));
        float4 v = ((const float4*)P)[i];
        #pragma unroll
        for (int s = 1; s < S; ++s) {
            float4 p = *(const float4*)(P + (size_t)s * MN + el);
            v.x += p.x; v.y += p.y; v.z += p.z; v.w += p.w;
        }
        #pragma unroll
        for (int e = 0; e < 8; ++e) {
            const float g = gate[b * 8 + e];
            float4 bb = *(const float4*)(bias + ((size_t)e << log2N) + n);
            v.x += g * bb.x; v.y += g * bb.y; v.z += g * bb.z; v.w += g * bb.w;
        }
        if (ELU_ACT) {
            v.x = v.x > 0.f ? v.x : expm1f(v.x);
            v.y = v.y > 0.f ? v.y : expm1f(v.y);
            v.z = v.z > 0.f ? v.z : expm1f(v.z);
            v.w = v.w > 0.f ? v.w : expm1f(v.w);
        }
        if (OUT_BF16) {
            ushort4 o; o.x = f2bf(v.x); o.y = f2bf(v.y); o.z = f2bf(v.z); o.w = f2bf(v.w);
            ((ushort4*)outp)[i] = o;
        } else {
            ((float4*)outp)[i] = v;
        }
    }
}

// ---------------- launcher ----------------------------------------------------
extern "C" void kernel_launch(void* const* d_in, const int* in_sizes, int n_in,
                              void* d_out, int out_size, void* d_ws, size_t ws_size,
                              hipStream_t stream) {
    const float* X  = (const float*)d_in[0];   // [8192,512]
    const float* W  = (const float*)d_in[1];   // [8192,8]
    const float* W1 = (const float*)d_in[2];   // [8,1024,512]
    const float* b1 = (const float*)d_in[3];   // [8,1024]
    const float* W2 = (const float*)d_in[4];   // [8,1024,1024]
    const float* b2 = (const float*)d_in[5];   // [8,1024]
    const float* W3 = (const float*)d_in[6];   // [8,512,1024]
    const float* b3 = (const float*)d_in[7];   // [8,512]
    float* out = (float*)d_out;

    char* ws = (char*)d_ws;
    u16* W1b  = (u16*)ws;  ws += (size_t)8 * 1024 * 512 * 2;     //  8.4 MB
    u16* W2b  = (u16*)ws;  ws += (size_t)8 * 1024 * 1024 * 2;    // 16.8 MB
    u16* W3b  = (u16*)ws;  ws += (size_t)8 * 512 * 1024 * 2;     //  8.4 MB
    u16* mid1 = (u16*)ws;  ws += (size_t)8192 * 1024 * 2;        // 16.8 MB
    u16* mid2 = (u16*)ws;  ws += (size_t)8192 * 1024 * 2;        // 16.8 MB
    u16* At1  = (u16*)ws;  ws += (size_t)8192 * 4096 * 2;        //   67 MB
    u16* At2  = (u16*)ws;  ws += (size_t)8192 * 8192 * 2;        //  134 MB

    // partial slabs reuse dead regions (each 67 MB):
    float* P1 = (float*)At2;   // live: L1 gemm -> L1 reduce (before atilde2 writes At2)
    float* P2 = (float*)At1;   // live: L2 gemm -> L2 reduce (At1 dead after L1 gemm)
    float* P3 = (float*)At1;   // live: L3 gemm -> L3 reduce (P2 consumed)

    // weight converts
    cvt_f32_bf16<<<4096, 256, 0, stream>>>(W1, W1b, 4194304 / 4);
    cvt_f32_bf16<<<8192, 256, 0, stream>>>(W2, W2b, 8388608 / 4);
    cvt_f32_bf16<<<4096, 256, 0, stream>>>(W3, W3b, 4194304 / 4);

    dim3 blk(256);

    // L1: At1 = gate ⊙ X [8192,4096]; split-K S=2 GEMM; reduce -> mid1 (ELU bf16)
    make_atilde_f32<<<16384, blk, 0, stream>>>(X, W, At1, 9);
    moe_gemm_sk<<<1024, blk, 0, stream>>>(At1, W1b, P1, 1024, 512, 4096, 3, 8, 3, 1, 32);
    moe_reduce<2, true, true><<<2048, blk, 0, stream>>>(P1, W, b1, (void*)mid1, 10, 8192 * 1024 / 4);

    // L2: At2 = gate ⊙ mid1 [8192,8192]; split-K S=2; reduce -> mid2 (ELU bf16)
    make_atilde_bf16<<<32768, blk, 0, stream>>>(mid1, W, At2, 10);
    moe_gemm_sk<<<1024, blk, 0, stream>>>(At2, W2b, P2, 1024, 1024, 8192, 4, 8, 3, 1, 64);
    moe_reduce<2, true, true><<<2048, blk, 0, stream>>>(P2, W, b2, (void*)mid2, 10, 8192 * 1024 / 4);

    // L3: At3 = gate ⊙ mid2 [8192,8192] (At2 reuse); split-K S=4; reduce -> out (f32)
    make_atilde_bf16<<<32768, blk, 0, stream>>>(mid2, W, At2, 10);
    moe_gemm_sk<<<1024, blk, 0, stream>>>(At2, W3b, P3, 512, 1024, 8192, 4, 8, 2, 2, 32);
    moe_reduce<4, false, false><<<2048, blk, 0, stream>>>(P3, W, b3, (void*)out, 9, 8192 * 512 / 4);
}

// Round 6
// 402.144 us; speedup vs baseline: 9.3243x; 1.0747x over previous
//
#include <hip/hip_runtime.h>
#include <hip/hip_bf16.h>
#include <cstdint>
#include <cstddef>

typedef __attribute__((ext_vector_type(8))) short bf16x8;
typedef __attribute__((ext_vector_type(8))) unsigned short u16x8;
typedef __attribute__((ext_vector_type(4))) float f32x4;
typedef unsigned short u16;

__device__ __forceinline__ u16 f2bf(float f) {
    unsigned int u = __float_as_uint(f);
    u += 0x7fffu + ((u >> 16) & 1u);   // RNE
    return (u16)(u >> 16);
}
__device__ __forceinline__ float bf2f(u16 u) {
    return __uint_as_float(((unsigned int)u) << 16);
}

__device__ __forceinline__ void gload16(const void* g, void* l) {
    __builtin_amdgcn_global_load_lds((const __attribute__((address_space(1))) void*)g,
                                     (__attribute__((address_space(3))) void*)l,
                                     16, 0, 0);
}

// ---------------- f32 -> bf16 convert (weights) -------------------------------
__global__ void cvt_f32_bf16(const float* __restrict__ in, u16* __restrict__ out, int n4) {
    int i = blockIdx.x * blockDim.x + threadIdx.x;
    if (i < n4) {
        float4 v = ((const float4*)in)[i];
        ushort4 o;
        o.x = f2bf(v.x); o.y = f2bf(v.y); o.z = f2bf(v.z); o.w = f2bf(v.w);
        ((ushort4*)out)[i] = o;
    }
}

// ---------------- gated-A materialization: At[b, e*K+k] = g[b,e]*A[b,k] -------
__global__ void make_atilde_f32(const float* __restrict__ A, const float* __restrict__ gate,
                                u16* __restrict__ out, int log2K) {
    const size_t idx = ((size_t)blockIdx.x * 256 + threadIdx.x) * 8;
    const int K = 1 << log2K;
    const size_t b = idx >> (log2K + 3);
    const int rem = (int)(idx - (b << (log2K + 3)));
    const int e = rem >> log2K;
    const int k = rem & (K - 1);
    const float g = gate[b * 8 + e];
    const float* src = A + b * (size_t)K + k;
    float4 v0 = ((const float4*)src)[0];
    float4 v1 = ((const float4*)src)[1];
    u16x8 r;
    r[0] = f2bf(g * v0.x); r[1] = f2bf(g * v0.y); r[2] = f2bf(g * v0.z); r[3] = f2bf(g * v0.w);
    r[4] = f2bf(g * v1.x); r[5] = f2bf(g * v1.y); r[6] = f2bf(g * v1.z); r[7] = f2bf(g * v1.w);
    *(u16x8*)(out + idx) = r;
}

__global__ void make_atilde_bf16(const u16* __restrict__ A, const float* __restrict__ gate,
                                 u16* __restrict__ out, int log2K) {
    const size_t idx = ((size_t)blockIdx.x * 256 + threadIdx.x) * 8;
    const int K = 1 << log2K;
    const size_t b = idx >> (log2K + 3);
    const int rem = (int)(idx - (b << (log2K + 3)));
    const int e = rem >> log2K;
    const int k = rem & (K - 1);
    const float g = gate[b * 8 + e];
    u16x8 a = *(const u16x8*)(A + b * (size_t)K + k);
    u16x8 r;
    #pragma unroll
    for (int j = 0; j < 8; ++j) r[j] = f2bf(g * bf2f(a[j]));
    *(u16x8*)(out + idx) = r;
}

// ---------------- 256x256 8-phase split-K GEMM over gated-A -------------------
// P[s][b][n] = sum_{kt in seg s} At-slice · Bw-slice (raw f32 partials).
// 512 threads = 8 waves (2M x 4N); per-wave output 128x64; BK=64.
// LDS 128 KB: buf x { A: 2 halves 128x64 | B: 2 halves 128x64 }, XOR-swizzled
// 128B rows. Counted-vmcnt pipeline: stage B(t+1)@q0, A(t+2)@q3, vmcnt(4)@q3.
__global__ __launch_bounds__(512, 2)
void moe_gemm_8p(const u16* __restrict__ At, const u16* __restrict__ Bw,
                 float* __restrict__ P,
                 int N, int K, int Ktot, int log2nk, int kts, int bxbits) {
    __shared__ char lds[2][65536];

    const int tid  = threadIdx.x;
    const int lane = tid & 63;
    const int wave = tid >> 6;
    const int wm   = wave >> 2;          // 0..1  (M half)
    const int wn   = wave & 3;           // 0..3  (N quarter)
    const int fr   = lane & 15;
    const int fg   = lane >> 4;
    const int swz  = (fr & 7) << 4;

    // XCD-chunked swizzle over exactly 256 blocks (32 per XCD)
    const int bid  = blockIdx.x;
    const int wgid = (bid & 7) * 32 + (bid >> 3);
    const int bx   = wgid & ((1 << bxbits) - 1);
    const int by   = (wgid >> bxbits) & 31;
    const int s    = wgid >> (bxbits + 5);
    const int m0   = by * 256;
    const int n0   = bx * 256;

    // per-thread staging offsets: 2 chunks per half-tile (1024B per wave-load)
    int rowA[2], rowB[2], ldso[2];
    #pragma unroll
    for (int it = 0; it < 2; ++it) {
        const int o  = (it * 8 + wave) * 1024 + lane * 16;
        const int r  = o >> 7;                    // 128B per row
        const int cb = (o & 127) ^ ((r & 7) << 4);  // inverse-swizzled src col
        rowA[it] = r * (Ktot * 2) + cb;
        rowB[it] = r * (K * 2) + cb;
        ldso[it] = o;
    }

    const char* Ab0 = (const char*)(At + (size_t)m0 * Ktot);
    const char* Ab1 = Ab0 + (size_t)128 * Ktot * 2;
    const char* Bb0 = (const char*)(Bw + (size_t)n0 * K);
    const char* Bb1 = Bb0 + (size_t)128 * K * 2;
    const size_t Best = (size_t)N * K * 2;
    const int nkm = (1 << log2nk) - 1;
    const int kt0 = s * kts;

#define STAGE_A(BUF, KTG) do { \
    const char* _a0 = Ab0 + (size_t)(KTG) * 128; \
    const char* _a1 = Ab1 + (size_t)(KTG) * 128; \
    char* _l = lds[BUF]; \
    gload16(_a0 + rowA[0], _l + ldso[0]); \
    gload16(_a0 + rowA[1], _l + ldso[1]); \
    gload16(_a1 + rowA[0], _l + 16384 + ldso[0]); \
    gload16(_a1 + rowA[1], _l + 16384 + ldso[1]); \
} while (0)

#define STAGE_B(BUF, KTG) do { \
    const int _kg = (KTG); \
    const size_t _bo = (size_t)(_kg >> log2nk) * Best + (size_t)(_kg & nkm) * 128; \
    char* _l = lds[BUF] + 32768; \
    gload16(Bb0 + _bo + rowB[0], _l + ldso[0]); \
    gload16(Bb0 + _bo + rowB[1], _l + ldso[1]); \
    gload16(Bb1 + _bo + rowB[0], _l + 16384 + ldso[0]); \
    gload16(Bb1 + _bo + rowB[1], _l + 16384 + ldso[1]); \
} while (0)

#define PH_BAR() do { \
    __builtin_amdgcn_sched_barrier(0); \
    __builtin_amdgcn_s_barrier(); \
    __builtin_amdgcn_sched_barrier(0); \
} while (0)

    f32x4 acc[8][4];
    #pragma unroll
    for (int i = 0; i < 8; ++i)
        #pragma unroll
        for (int j = 0; j < 4; ++j) acc[i][j] = f32x4{0.f, 0.f, 0.f, 0.f};

    bf16x8 af[2][4], bfA[2][2], bfB[2][2];

    // prologue: tile0 A+B -> buf0, tile1 A -> buf1; wait tile0 (4 newest may fly)
    STAGE_A(0, kt0);
    STAGE_B(0, kt0);
    STAGE_A(1, kt0 + 1);
    __builtin_amdgcn_sched_barrier(0);
    asm volatile("s_waitcnt vmcnt(4)" ::: "memory");
    __builtin_amdgcn_s_barrier();
    __builtin_amdgcn_sched_barrier(0);

#define FRAME(BUF, TREL) do { \
    const int _tr = (TREL); \
    const char* _abase = lds[BUF] + wm * 16384 + fr * 128; \
    const char* _bbase = lds[BUF] + 32768 + (wn >> 1) * 16384 + ((wn & 1) * 64 + fr) * 128; \
    const int _k0 = (fg * 16) ^ swz; \
    const int _k1 = (64 + fg * 16) ^ swz; \
    /* ---- q0: read A-lo frags + B-lo frags; stage B(t+1) ---- */ \
    _Pragma("unroll") for (int i = 0; i < 4; ++i) { \
        af[0][i] = *(const bf16x8*)(_abase + i * 2048 + _k0); \
        af[1][i] = *(const bf16x8*)(_abase + i * 2048 + _k1); } \
    _Pragma("unroll") for (int j = 0; j < 2; ++j) { \
        bfA[0][j] = *(const bf16x8*)(_bbase + j * 2048 + _k0); \
        bfA[1][j] = *(const bf16x8*)(_bbase + j * 2048 + _k1); } \
    if (_tr + 1 < kts) STAGE_B((BUF) ^ 1, kt0 + _tr + 1); \
    PH_BAR(); \
    __builtin_amdgcn_s_setprio(1); \
    _Pragma("unroll") for (int i = 0; i < 4; ++i) \
    _Pragma("unroll") for (int j = 0; j < 2; ++j) { \
        acc[i][j] = __builtin_amdgcn_mfma_f32_16x16x32_bf16(af[0][i], bfA[0][j], acc[i][j], 0, 0, 0); \
        acc[i][j] = __builtin_amdgcn_mfma_f32_16x16x32_bf16(af[1][i], bfA[1][j], acc[i][j], 0, 0, 0); } \
    __builtin_amdgcn_s_setprio(0); \
    PH_BAR(); \
    /* ---- q1: read B-hi frags; MFMA m-lo x n-hi ---- */ \
    _Pragma("unroll") for (int j = 0; j < 2; ++j) { \
        bfB[0][j] = *(const bf16x8*)(_bbase + (2 + j) * 2048 + _k0); \
        bfB[1][j] = *(const bf16x8*)(_bbase + (2 + j) * 2048 + _k1); } \
    PH_BAR(); \
    __builtin_amdgcn_s_setprio(1); \
    _Pragma("unroll") for (int i = 0; i < 4; ++i) \
    _Pragma("unroll") for (int j = 0; j < 2; ++j) { \
        acc[i][2 + j] = __builtin_amdgcn_mfma_f32_16x16x32_bf16(af[0][i], bfB[0][j], acc[i][2 + j], 0, 0, 0); \
        acc[i][2 + j] = __builtin_amdgcn_mfma_f32_16x16x32_bf16(af[1][i], bfB[1][j], acc[i][2 + j], 0, 0, 0); } \
    __builtin_amdgcn_s_setprio(0); \
    PH_BAR(); \
    /* ---- q2: read A-hi frags; MFMA m-hi x n-hi ---- */ \
    _Pragma("unroll") for (int i = 0; i < 4; ++i) { \
        af[0][i] = *(const bf16x8*)(_abase + (4 + i) * 2048 + _k0); \
        af[1][i] = *(const bf16x8*)(_abase + (4 + i) * 2048 + _k1); } \
    PH_BAR(); \
    __builtin_amdgcn_s_setprio(1); \
    _Pragma("unroll") for (int i = 0; i < 4; ++i) \
    _Pragma("unroll") for (int j = 0; j < 2; ++j) { \
        acc[4 + i][2 + j] = __builtin_amdgcn_mfma_f32_16x16x32_bf16(af[0][i], bfB[0][j], acc[4 + i][2 + j], 0, 0, 0); \
        acc[4 + i][2 + j] = __builtin_amdgcn_mfma_f32_16x16x32_bf16(af[1][i], bfB[1][j], acc[4 + i][2 + j], 0, 0, 0); } \
    __builtin_amdgcn_s_setprio(0); \
    PH_BAR(); \
    /* ---- q3: no reads (reuse af-hi, bfA); stage A(t+2); counted vmcnt ---- */ \
    if (_tr + 2 < kts) { \
        STAGE_A(BUF, kt0 + _tr + 2); \
        __builtin_amdgcn_sched_barrier(0); \
        asm volatile("s_waitcnt vmcnt(4)" ::: "memory"); \
    } else { \
        __builtin_amdgcn_sched_barrier(0); \
        asm volatile("s_waitcnt vmcnt(0)" ::: "memory"); \
    } \
    __builtin_amdgcn_s_barrier(); \
    __builtin_amdgcn_sched_barrier(0); \
    __builtin_amdgcn_s_setprio(1); \
    _Pragma("unroll") for (int i = 0; i < 4; ++i) \
    _Pragma("unroll") for (int j = 0; j < 2; ++j) { \
        acc[4 + i][j] = __builtin_amdgcn_mfma_f32_16x16x32_bf16(af[0][i], bfA[0][j], acc[4 + i][j], 0, 0, 0); \
        acc[4 + i][j] = __builtin_amdgcn_mfma_f32_16x16x32_bf16(af[1][i], bfA[1][j], acc[4 + i][j], 0, 0, 0); } \
    __builtin_amdgcn_s_setprio(0); \
    PH_BAR(); \
} while (0)

    for (int t = 0; t < kts; t += 2) {
        FRAME(0, t);
        FRAME(1, t + 1);
    }

    // epilogue: raw f32 partial store
    float* Pb = P + ((size_t)s * 8192 + m0 + wm * 128) * N + (n0 + wn * 64);
    #pragma unroll
    for (int mi = 0; mi < 8; ++mi)
        #pragma unroll
        for (int j = 0; j < 4; ++j) {
            const int r = mi * 16 + fg * 4 + j;
            #pragma unroll
            for (int ni = 0; ni < 4; ++ni)
                Pb[(size_t)r * N + ni * 16 + fr] = acc[mi][ni][j];
        }
#undef FRAME
#undef PH_BAR
#undef STAGE_A
#undef STAGE_B
}

// ---------------- split-K reduce: sum partials + gate-weighted bias + act -----
template<int S, bool ELU_ACT, bool OUT_BF16>
__global__ void moe_reduce(const float* __restrict__ P,
                           const float* __restrict__ gate,
                           const float* __restrict__ bias,
                           void* __restrict__ outp,
                           int log2N, int n4total) {
    const int stride = gridDim.x * blockDim.x;
    const size_t MN = ((size_t)n4total) * 4;
    for (int i = blockIdx.x * blockDim.x + threadIdx.x; i < n4total; i += stride) {
        const size_t el = (size_t)i * 4;
        const size_t b = el >> log2N;
        const int n = (int)(el & ((1 << log2N) - 1));
        float4 v = ((const float4*)P)[i];
        #pragma unroll
        for (int s = 1; s < S; ++s) {
            float4 p = *(const float4*)(P + (size_t)s * MN + el);
            v.x += p.x; v.y += p.y; v.z += p.z; v.w += p.w;
        }
        #pragma unroll
        for (int e = 0; e < 8; ++e) {
            const float g = gate[b * 8 + e];
            float4 bb = *(const float4*)(bias + ((size_t)e << log2N) + n);
            v.x += g * bb.x; v.y += g * bb.y; v.z += g * bb.z; v.w += g * bb.w;
        }
        if (ELU_ACT) {
            v.x = v.x > 0.f ? v.x : expm1f(v.x);
            v.y = v.y > 0.f ? v.y : expm1f(v.y);
            v.z = v.z > 0.f ? v.z : expm1f(v.z);
            v.w = v.w > 0.f ? v.w : expm1f(v.w);
        }
        if (OUT_BF16) {
            ushort4 o; o.x = f2bf(v.x); o.y = f2bf(v.y); o.z = f2bf(v.z); o.w = f2bf(v.w);
            ((ushort4*)outp)[i] = o;
        } else {
            ((float4*)outp)[i] = v;
        }
    }
}

// ---------------- launcher ----------------------------------------------------
extern "C" void kernel_launch(void* const* d_in, const int* in_sizes, int n_in,
                              void* d_out, int out_size, void* d_ws, size_t ws_size,
                              hipStream_t stream) {
    const float* X  = (const float*)d_in[0];   // [8192,512]
    const float* W  = (const float*)d_in[1];   // [8192,8]
    const float* W1 = (const float*)d_in[2];   // [8,1024,512]
    const float* b1 = (const float*)d_in[3];   // [8,1024]
    const float* W2 = (const float*)d_in[4];   // [8,1024,1024]
    const float* b2 = (const float*)d_in[5];   // [8,1024]
    const float* W3 = (const float*)d_in[6];   // [8,512,1024]
    const float* b3 = (const float*)d_in[7];   // [8,512]
    float* out = (float*)d_out;

    char* ws = (char*)d_ws;
    u16* W1b  = (u16*)ws;  ws += (size_t)8 * 1024 * 512 * 2;     //  8.4 MB
    u16* W2b  = (u16*)ws;  ws += (size_t)8 * 1024 * 1024 * 2;    // 16.8 MB
    u16* W3b  = (u16*)ws;  ws += (size_t)8 * 512 * 1024 * 2;     //  8.4 MB
    u16* mid1 = (u16*)ws;  ws += (size_t)8192 * 1024 * 2;        // 16.8 MB
    u16* mid2 = (u16*)ws;  ws += (size_t)8192 * 1024 * 2;        // 16.8 MB
    u16* At1  = (u16*)ws;  ws += (size_t)8192 * 4096 * 2;        //   67 MB
    u16* At2  = (u16*)ws;  ws += (size_t)8192 * 8192 * 2;        //  134 MB

    // partial slabs reuse dead regions (each <= 67 MB):
    float* P1 = (float*)At2;   // live: L1 gemm -> L1 reduce (before atilde2 writes At2)
    float* P2 = (float*)At1;   // live: L2 gemm -> L2 reduce (At1 dead after L1 gemm)
    float* P3 = (float*)At1;   // live: L3 gemm -> L3 reduce (P2 consumed)

    // weight converts
    cvt_f32_bf16<<<4096, 256, 0, stream>>>(W1, W1b, 4194304 / 4);
    cvt_f32_bf16<<<8192, 256, 0, stream>>>(W2, W2b, 8388608 / 4);
    cvt_f32_bf16<<<4096, 256, 0, stream>>>(W3, W3b, 4194304 / 4);

    dim3 blk(256);

    // L1: At1 = gate ⊙ X [8192,4096]; S=2 8-phase GEMM; reduce -> mid1 (ELU bf16)
    make_atilde_f32<<<16384, blk, 0, stream>>>(X, W, At1, 9);
    moe_gemm_8p<<<256, 512, 0, stream>>>(At1, W1b, P1, 1024, 512, 4096, 3, 32, 2);
    moe_reduce<2, true, true><<<2048, blk, 0, stream>>>(P1, W, b1, (void*)mid1, 10, 8192 * 1024 / 4);

    // L2: At2 = gate ⊙ mid1 [8192,8192]; S=2; reduce -> mid2 (ELU bf16)
    make_atilde_bf16<<<32768, blk, 0, stream>>>(mid1, W, At2, 10);
    moe_gemm_8p<<<256, 512, 0, stream>>>(At2, W2b, P2, 1024, 1024, 8192, 4, 64, 2);
    moe_reduce<2, true, true><<<2048, blk, 0, stream>>>(P2, W, b2, (void*)mid2, 10, 8192 * 1024 / 4);

    // L3: At3 = gate ⊙ mid2 [8192,8192] (At2 reuse); S=4; reduce -> out (f32)
    make_atilde_bf16<<<32768, blk, 0, stream>>>(mid2, W, At2, 10);
    moe_gemm_8p<<<256, 512, 0, stream>>>(At2, W3b, P3, 512, 1024, 8192, 4, 32, 1);
    moe_reduce<4, false, false><<<2048, blk, 0, stream>>>(P3, W, b3, (void*)out, 9, 8192 * 512 / 4);
}

// Round 7
// 378.439 us; speedup vs baseline: 9.9084x; 1.0626x over previous
//
#include <hip/hip_runtime.h>
#include <hip/hip_bf16.h>
#include <cstdint>
#include <cstddef>

typedef __attribute__((ext_vector_type(8))) short bf16x8;
typedef __attribute__((ext_vector_type(8))) unsigned short u16x8;
typedef __attribute__((ext_vector_type(4))) float f32x4;
typedef unsigned short u16;

__device__ __forceinline__ u16 f2bf(float f) {
    unsigned int u = __float_as_uint(f);
    u += 0x7fffu + ((u >> 16) & 1u);   // RNE
    return (u16)(u >> 16);
}
__device__ __forceinline__ float bf2f(u16 u) {
    return __uint_as_float(((unsigned int)u) << 16);
}

__device__ __forceinline__ void gload16(const void* g, void* l) {
    __builtin_amdgcn_global_load_lds((const __attribute__((address_space(1))) void*)g,
                                     (__attribute__((address_space(3))) void*)l,
                                     16, 0, 0);
}

// ---------------- f32 -> bf16 convert (weights) -------------------------------
__global__ void cvt_f32_bf16(const float* __restrict__ in, u16* __restrict__ out, int n4) {
    int i = blockIdx.x * blockDim.x + threadIdx.x;
    if (i < n4) {
        float4 v = ((const float4*)in)[i];
        ushort4 o;
        o.x = f2bf(v.x); o.y = f2bf(v.y); o.z = f2bf(v.z); o.w = f2bf(v.w);
        ((ushort4*)out)[i] = o;
    }
}

// ---------------- gated-A materialization: At[b, e*K+k] = g[b,e]*A[b,k] -------
__global__ void make_atilde_f32(const float* __restrict__ A, const float* __restrict__ gate,
                                u16* __restrict__ out, int log2K) {
    const size_t idx = ((size_t)blockIdx.x * 256 + threadIdx.x) * 8;
    const int K = 1 << log2K;
    const size_t b = idx >> (log2K + 3);
    const int rem = (int)(idx - (b << (log2K + 3)));
    const int e = rem >> log2K;
    const int k = rem & (K - 1);
    const float g = gate[b * 8 + e];
    const float* src = A + b * (size_t)K + k;
    float4 v0 = ((const float4*)src)[0];
    float4 v1 = ((const float4*)src)[1];
    u16x8 r;
    r[0] = f2bf(g * v0.x); r[1] = f2bf(g * v0.y); r[2] = f2bf(g * v0.z); r[3] = f2bf(g * v0.w);
    r[4] = f2bf(g * v1.x); r[5] = f2bf(g * v1.y); r[6] = f2bf(g * v1.z); r[7] = f2bf(g * v1.w);
    *(u16x8*)(out + idx) = r;
}

__global__ void make_atilde_bf16(const u16* __restrict__ A, const float* __restrict__ gate,
                                 u16* __restrict__ out, int log2K) {
    const size_t idx = ((size_t)blockIdx.x * 256 + threadIdx.x) * 8;
    const int K = 1 << log2K;
    const size_t b = idx >> (log2K + 3);
    const int rem = (int)(idx - (b << (log2K + 3)));
    const int e = rem >> log2K;
    const int k = rem & (K - 1);
    const float g = gate[b * 8 + e];
    u16x8 a = *(const u16x8*)(A + b * (size_t)K + k);
    u16x8 r;
    #pragma unroll
    for (int j = 0; j < 8; ++j) r[j] = f2bf(g * bf2f(a[j]));
    *(u16x8*)(out + idx) = r;
}

// ---------------- 256x256 split-K GEMM, 2-barrier free-run frame --------------
// P[s][b][n] = sum_{kt in seg s} At-slice · Bw-slice (raw f32 partials).
// 512 threads = 8 waves (2M x 4N); per-wave output 128x64; BK=64.
// LDS 128 KB: buf x { A 2x[128x64] | B 2x[128x64] }, XOR-swizzled 128B rows.
// Frame t: STAGE_B(t+1)@top; reads+MFMA quadrants free-run (no inter-phase
// barriers); BAR(1) after all LDS reads; STAGE_A(t+2); reg-only hi-lo MFMA;
// vmcnt(4) (drains A(t+1)+B(t+1), A(t+2) stays in flight); BAR(2).
__global__ __launch_bounds__(512, 2)
void moe_gemm_2b(const u16* __restrict__ At, const u16* __restrict__ Bw,
                 float* __restrict__ P,
                 int N, int K, int Ktot, int log2nk, int kts, int bxbits) {
    __shared__ char lds[2][65536];

    const int tid  = threadIdx.x;
    const int lane = tid & 63;
    const int wave = tid >> 6;
    const int wm   = wave >> 2;          // 0..1  (M half)
    const int wn   = wave & 3;           // 0..3  (N quarter)
    const int fr   = lane & 15;
    const int fg   = lane >> 4;
    const int swz  = (fr & 7) << 4;

    // XCD-chunked swizzle over exactly 256 blocks (32 per XCD)
    const int bid  = blockIdx.x;
    const int wgid = (bid & 7) * 32 + (bid >> 3);
    const int bx   = wgid & ((1 << bxbits) - 1);
    const int by   = (wgid >> bxbits) & 31;
    const int s    = wgid >> (bxbits + 5);
    const int m0   = by * 256;
    const int n0   = bx * 256;

    // per-thread staging offsets
    int rowA[2], rowB[2], ldso[2];
    #pragma unroll
    for (int it = 0; it < 2; ++it) {
        const int o  = (it * 8 + wave) * 1024 + lane * 16;
        const int r  = o >> 7;                      // 128B per row
        const int cb = (o & 127) ^ ((r & 7) << 4);  // inverse-swizzled src col
        rowA[it] = r * (Ktot * 2) + cb;
        rowB[it] = r * (K * 2) + cb;
        ldso[it] = o;
    }

    const char* Ab0 = (const char*)(At + (size_t)m0 * Ktot);
    const char* Ab1 = Ab0 + (size_t)128 * Ktot * 2;
    const char* Bb0 = (const char*)(Bw + (size_t)n0 * K);
    const char* Bb1 = Bb0 + (size_t)128 * K * 2;
    const size_t Best = (size_t)N * K * 2;
    const int nkm = (1 << log2nk) - 1;
    const int kt0 = s * kts;

#define STAGE_A(BUF, KTG) do { \
    const char* _a0 = Ab0 + (size_t)(KTG) * 128; \
    const char* _a1 = Ab1 + (size_t)(KTG) * 128; \
    char* _l = lds[BUF]; \
    gload16(_a0 + rowA[0], _l + ldso[0]); \
    gload16(_a0 + rowA[1], _l + ldso[1]); \
    gload16(_a1 + rowA[0], _l + 16384 + ldso[0]); \
    gload16(_a1 + rowA[1], _l + 16384 + ldso[1]); \
} while (0)

#define STAGE_B(BUF, KTG) do { \
    const int _kg = (KTG); \
    const size_t _bo = (size_t)(_kg >> log2nk) * Best + (size_t)(_kg & nkm) * 128; \
    char* _l = lds[BUF] + 32768; \
    gload16(Bb0 + _bo + rowB[0], _l + ldso[0]); \
    gload16(Bb0 + _bo + rowB[1], _l + ldso[1]); \
    gload16(Bb1 + _bo + rowB[0], _l + 16384 + ldso[0]); \
    gload16(Bb1 + _bo + rowB[1], _l + 16384 + ldso[1]); \
} while (0)

    f32x4 acc[8][4];
    #pragma unroll
    for (int i = 0; i < 8; ++i)
        #pragma unroll
        for (int j = 0; j < 4; ++j) acc[i][j] = f32x4{0.f, 0.f, 0.f, 0.f};

    bf16x8 af[2][4], bfA[2][2], bfB[2][2];

    // prologue: A(0)+B(0) -> buf0, A(1) -> buf1; drain first tile, A(1) may fly
    STAGE_A(0, kt0);
    STAGE_B(0, kt0);
    STAGE_A(1, kt0 + 1);
    __builtin_amdgcn_sched_barrier(0);
    asm volatile("s_waitcnt vmcnt(4)" ::: "memory");
    __builtin_amdgcn_s_barrier();
    __builtin_amdgcn_sched_barrier(0);

    for (int t = 0; t < kts; ++t) {
        const int BUF = t & 1;
        const char* _abase = lds[BUF] + wm * 16384 + fr * 128;
        const char* _bbase = lds[BUF] + 32768 + (wn >> 1) * 16384 + ((wn & 1) * 64 + fr) * 128;
        const int k0 = (fg * 16) ^ swz;
        const int k1 = (64 + fg * 16) ^ swz;

        if (t + 1 < kts) STAGE_B(BUF ^ 1, kt0 + t + 1);

        // af-lo + bfA reads, MFMA lo x lo
        #pragma unroll
        for (int i = 0; i < 4; ++i) {
            af[0][i] = *(const bf16x8*)(_abase + i * 2048 + k0);
            af[1][i] = *(const bf16x8*)(_abase + i * 2048 + k1);
        }
        #pragma unroll
        for (int j = 0; j < 2; ++j) {
            bfA[0][j] = *(const bf16x8*)(_bbase + j * 2048 + k0);
            bfA[1][j] = *(const bf16x8*)(_bbase + j * 2048 + k1);
        }
        __builtin_amdgcn_s_setprio(1);
        #pragma unroll
        for (int i = 0; i < 4; ++i)
            #pragma unroll
            for (int j = 0; j < 2; ++j) {
                acc[i][j] = __builtin_amdgcn_mfma_f32_16x16x32_bf16(af[0][i], bfA[0][j], acc[i][j], 0, 0, 0);
                acc[i][j] = __builtin_amdgcn_mfma_f32_16x16x32_bf16(af[1][i], bfA[1][j], acc[i][j], 0, 0, 0);
            }
        __builtin_amdgcn_s_setprio(0);

        // bfB reads, MFMA lo x hi
        #pragma unroll
        for (int j = 0; j < 2; ++j) {
            bfB[0][j] = *(const bf16x8*)(_bbase + (2 + j) * 2048 + k0);
            bfB[1][j] = *(const bf16x8*)(_bbase + (2 + j) * 2048 + k1);
        }
        __builtin_amdgcn_s_setprio(1);
        #pragma unroll
        for (int i = 0; i < 4; ++i)
            #pragma unroll
            for (int j = 0; j < 2; ++j) {
                acc[i][2 + j] = __builtin_amdgcn_mfma_f32_16x16x32_bf16(af[0][i], bfB[0][j], acc[i][2 + j], 0, 0, 0);
                acc[i][2 + j] = __builtin_amdgcn_mfma_f32_16x16x32_bf16(af[1][i], bfB[1][j], acc[i][2 + j], 0, 0, 0);
            }
        __builtin_amdgcn_s_setprio(0);

        // af-hi reads, MFMA hi x hi
        #pragma unroll
        for (int i = 0; i < 4; ++i) {
            af[0][i] = *(const bf16x8*)(_abase + (4 + i) * 2048 + k0);
            af[1][i] = *(const bf16x8*)(_abase + (4 + i) * 2048 + k1);
        }
        __builtin_amdgcn_s_setprio(1);
        #pragma unroll
        for (int i = 0; i < 4; ++i)
            #pragma unroll
            for (int j = 0; j < 2; ++j) {
                acc[4 + i][2 + j] = __builtin_amdgcn_mfma_f32_16x16x32_bf16(af[0][i], bfB[0][j], acc[4 + i][2 + j], 0, 0, 0);
                acc[4 + i][2 + j] = __builtin_amdgcn_mfma_f32_16x16x32_bf16(af[1][i], bfB[1][j], acc[4 + i][2 + j], 0, 0, 0);
            }
        __builtin_amdgcn_s_setprio(0);

        // BAR(1): all waves' LDS reads of lds[BUF] complete (reads were
        // consumed by the MFMAs above -> lgkmcnt drained per-wave).
        __builtin_amdgcn_sched_barrier(0);
        __builtin_amdgcn_s_barrier();
        __builtin_amdgcn_sched_barrier(0);

        if (t + 2 < kts) STAGE_A(BUF, kt0 + t + 2);   // into just-freed A region

        // register-only MFMA hi x lo (covers STAGE_A issue + vmcnt wait)
        __builtin_amdgcn_s_setprio(1);
        #pragma unroll
        for (int i = 0; i < 4; ++i)
            #pragma unroll
            for (int j = 0; j < 2; ++j) {
                acc[4 + i][j] = __builtin_amdgcn_mfma_f32_16x16x32_bf16(af[0][i], bfA[0][j], acc[4 + i][j], 0, 0, 0);
                acc[4 + i][j] = __builtin_amdgcn_mfma_f32_16x16x32_bf16(af[1][i], bfA[1][j], acc[4 + i][j], 0, 0, 0);
            }
        __builtin_amdgcn_s_setprio(0);

        __builtin_amdgcn_sched_barrier(0);
        if (t + 2 < kts) {
            asm volatile("s_waitcnt vmcnt(4)" ::: "memory");  // drain A(t+1),B(t+1)
        } else {
            asm volatile("s_waitcnt vmcnt(0)" ::: "memory");  // tail
        }
        __builtin_amdgcn_s_barrier();
        __builtin_amdgcn_sched_barrier(0);
    }

    // epilogue: raw f32 partial store
    float* Pb = P + ((size_t)s * 8192 + m0 + wm * 128) * N + (n0 + wn * 64);
    #pragma unroll
    for (int mi = 0; mi < 8; ++mi)
        #pragma unroll
        for (int j = 0; j < 4; ++j) {
            const int r = mi * 16 + fg * 4 + j;
            #pragma unroll
            for (int ni = 0; ni < 4; ++ni)
                Pb[(size_t)r * N + ni * 16 + fr] = acc[mi][ni][j];
        }
#undef STAGE_A
#undef STAGE_B
}

// ---------------- split-K reduce: sum partials + gate-weighted bias + act -----
template<int S, bool ELU_ACT, bool OUT_BF16>
__global__ void moe_reduce(const float* __restrict__ P,
                           const float* __restrict__ gate,
                           const float* __restrict__ bias,
                           void* __restrict__ outp,
                           int log2N, int n4total) {
    const int stride = gridDim.x * blockDim.x;
    const size_t MN = ((size_t)n4total) * 4;
    for (int i = blockIdx.x * blockDim.x + threadIdx.x; i < n4total; i += stride) {
        const size_t el = (size_t)i * 4;
        const size_t b = el >> log2N;
        const int n = (int)(el & ((1 << log2N) - 1));
        float4 v = ((const float4*)P)[i];
        #pragma unroll
        for (int s = 1; s < S; ++s) {
            float4 p = *(const float4*)(P + (size_t)s * MN + el);
            v.x += p.x; v.y += p.y; v.z += p.z; v.w += p.w;
        }
        #pragma unroll
        for (int e = 0; e < 8; ++e) {
            const float g = gate[b * 8 + e];
            float4 bb = *(const float4*)(bias + ((size_t)e << log2N) + n);
            v.x += g * bb.x; v.y += g * bb.y; v.z += g * bb.z; v.w += g * bb.w;
        }
        if (ELU_ACT) {
            v.x = v.x > 0.f ? v.x : expm1f(v.x);
            v.y = v.y > 0.f ? v.y : expm1f(v.y);
            v.z = v.z > 0.f ? v.z : expm1f(v.z);
            v.w = v.w > 0.f ? v.w : expm1f(v.w);
        }
        if (OUT_BF16) {
            ushort4 o; o.x = f2bf(v.x); o.y = f2bf(v.y); o.z = f2bf(v.z); o.w = f2bf(v.w);
            ((ushort4*)outp)[i] = o;
        } else {
            ((float4*)outp)[i] = v;
        }
    }
}

// ---- fused: reduce(S=2, bias b2, ELU) + atilde (gate-scale, 8 expert copies) -
// P: [2][8192][1024] f32; At: [8192][8*1024] bf16. Thread = 8 h of one row.
__global__ void reduce_atilde2(const float* __restrict__ P,
                               const float* __restrict__ gate,
                               const float* __restrict__ bias,
                               u16* __restrict__ At) {
    const int idx = blockIdx.x * 256 + threadIdx.x;   // 8192*128 total
    const int h = (idx & 127) * 8;
    const size_t b = idx >> 7;
    const size_t MH = (size_t)8192 * 1024;
    const float* p = P + b * 1024 + h;
    float4 v0 = ((const float4*)p)[0];
    float4 v1 = ((const float4*)p)[1];
    {
        const float* p1 = p + MH;
        float4 a0 = ((const float4*)p1)[0], a1 = ((const float4*)p1)[1];
        v0.x += a0.x; v0.y += a0.y; v0.z += a0.z; v0.w += a0.w;
        v1.x += a1.x; v1.y += a1.y; v1.z += a1.z; v1.w += a1.w;
    }
    float4 g0 = *(const float4*)&gate[b * 8];
    float4 g1 = *(const float4*)&gate[b * 8 + 4];
    float gg[8] = {g0.x, g0.y, g0.z, g0.w, g1.x, g1.y, g1.z, g1.w};
    #pragma unroll
    for (int e = 0; e < 8; ++e) {
        const float* bb = bias + e * 1024 + h;
        float4 b0 = ((const float4*)bb)[0], b1 = ((const float4*)bb)[1];
        v0.x += gg[e] * b0.x; v0.y += gg[e] * b0.y; v0.z += gg[e] * b0.z; v0.w += gg[e] * b0.w;
        v1.x += gg[e] * b1.x; v1.y += gg[e] * b1.y; v1.z += gg[e] * b1.z; v1.w += gg[e] * b1.w;
    }
    float m[8] = {v0.x, v0.y, v0.z, v0.w, v1.x, v1.y, v1.z, v1.w};
    #pragma unroll
    for (int j = 0; j < 8; ++j) m[j] = m[j] > 0.f ? m[j] : expm1f(m[j]);
    u16* o = At + b * 8192 + h;
    #pragma unroll
    for (int e = 0; e < 8; ++e) {
        u16x8 r;
        #pragma unroll
        for (int j = 0; j < 8; ++j) r[j] = f2bf(gg[e] * m[j]);
        *(u16x8*)(o + e * 1024) = r;
    }
}

// ---------------- launcher ----------------------------------------------------
extern "C" void kernel_launch(void* const* d_in, const int* in_sizes, int n_in,
                              void* d_out, int out_size, void* d_ws, size_t ws_size,
                              hipStream_t stream) {
    const float* X  = (const float*)d_in[0];   // [8192,512]
    const float* W  = (const float*)d_in[1];   // [8192,8]
    const float* W1 = (const float*)d_in[2];   // [8,1024,512]
    const float* b1 = (const float*)d_in[3];   // [8,1024]
    const float* W2 = (const float*)d_in[4];   // [8,1024,1024]
    const float* b2 = (const float*)d_in[5];   // [8,1024]
    const float* W3 = (const float*)d_in[6];   // [8,512,1024]
    const float* b3 = (const float*)d_in[7];   // [8,512]
    float* out = (float*)d_out;

    char* ws = (char*)d_ws;
    u16* W1b  = (u16*)ws;  ws += (size_t)8 * 1024 * 512 * 2;     //  8.4 MB
    u16* W2b  = (u16*)ws;  ws += (size_t)8 * 1024 * 1024 * 2;    // 16.8 MB
    u16* W3b  = (u16*)ws;  ws += (size_t)8 * 512 * 1024 * 2;     //  8.4 MB
    u16* mid1 = (u16*)ws;  ws += (size_t)8192 * 1024 * 2;        // 16.8 MB
    u16* mid2 = (u16*)ws;  ws += (size_t)8192 * 1024 * 2;        // 16.8 MB (unused)
    u16* At1  = (u16*)ws;  ws += (size_t)8192 * 4096 * 2;        //   67 MB
    u16* At2  = (u16*)ws;  ws += (size_t)8192 * 8192 * 2;        //  134 MB
    (void)mid2;

    // partial slabs reuse dead regions:
    float* P1 = (float*)At2;   // L1 gemm -> L1 reduce (before atilde2 writes At2)
    float* P2 = (float*)At1;   // L2 gemm -> fused reduce2/atilde3 (At1 dead)
    float* P3 = (float*)At1;   // L3 gemm -> L3 reduce (P2 consumed)

    // weight converts
    cvt_f32_bf16<<<4096, 256, 0, stream>>>(W1, W1b, 4194304 / 4);
    cvt_f32_bf16<<<8192, 256, 0, stream>>>(W2, W2b, 8388608 / 4);
    cvt_f32_bf16<<<4096, 256, 0, stream>>>(W3, W3b, 4194304 / 4);

    dim3 blk(256);

    // L1: At1 = gate ⊙ X [8192,4096]; S=2 GEMM; reduce -> mid1 (ELU bf16)
    make_atilde_f32<<<16384, blk, 0, stream>>>(X, W, At1, 9);
    moe_gemm_2b<<<256, 512, 0, stream>>>(At1, W1b, P1, 1024, 512, 4096, 3, 32, 2);
    moe_reduce<2, true, true><<<2048, blk, 0, stream>>>(P1, W, b1, (void*)mid1, 10, 8192 * 1024 / 4);

    // L2: At2 = gate ⊙ mid1 [8192,8192]; S=2 GEMM; fused reduce+atilde -> At3(=At2)
    make_atilde_bf16<<<32768, blk, 0, stream>>>(mid1, W, At2, 10);
    moe_gemm_2b<<<256, 512, 0, stream>>>(At2, W2b, P2, 1024, 1024, 8192, 4, 64, 2);
    reduce_atilde2<<<4096, blk, 0, stream>>>(P2, W, b2, At2);

    // L3: GEMM over At2; S=4; reduce -> out (f32)
    moe_gemm_2b<<<256, 512, 0, stream>>>(At2, W3b, P3, 512, 1024, 8192, 4, 32, 1);
    moe_reduce<4, false, false><<<2048, blk, 0, stream>>>(P3, W, b3, (void*)out, 9, 8192 * 512 / 4);
}

// Round 8
// 374.943 us; speedup vs baseline: 10.0008x; 1.0093x over previous
//
#include <hip/hip_runtime.h>
#include <hip/hip_bf16.h>
#include <cstdint>
#include <cstddef>

typedef __attribute__((ext_vector_type(8))) short bf16x8;
typedef __attribute__((ext_vector_type(8))) unsigned short u16x8;
typedef __attribute__((ext_vector_type(4))) float f32x4;
typedef unsigned short u16;

__device__ __forceinline__ u16 f2bf(float f) {
    unsigned int u = __float_as_uint(f);
    u += 0x7fffu + ((u >> 16) & 1u);   // RNE
    return (u16)(u >> 16);
}
__device__ __forceinline__ float bf2f(u16 u) {
    return __uint_as_float(((unsigned int)u) << 16);
}

__device__ __forceinline__ void gload16(const void* g, void* l) {
    __builtin_amdgcn_global_load_lds((const __attribute__((address_space(1))) void*)g,
                                     (__attribute__((address_space(3))) void*)l,
                                     16, 0, 0);
}

// ---------------- f32 -> bf16 convert (weights) -------------------------------
__global__ void cvt_f32_bf16(const float* __restrict__ in, u16* __restrict__ out, int n4) {
    int i = blockIdx.x * blockDim.x + threadIdx.x;
    if (i < n4) {
        float4 v = ((const float4*)in)[i];
        ushort4 o;
        o.x = f2bf(v.x); o.y = f2bf(v.y); o.z = f2bf(v.z); o.w = f2bf(v.w);
        ((ushort4*)out)[i] = o;
    }
}

// ---------------- gated-A materialization: At[b, e*K+k] = g[b,e]*A[b,k] -------
__global__ void make_atilde_f32(const float* __restrict__ A, const float* __restrict__ gate,
                                u16* __restrict__ out, int log2K) {
    const size_t idx = ((size_t)blockIdx.x * 256 + threadIdx.x) * 8;
    const int K = 1 << log2K;
    const size_t b = idx >> (log2K + 3);
    const int rem = (int)(idx - (b << (log2K + 3)));
    const int e = rem >> log2K;
    const int k = rem & (K - 1);
    const float g = gate[b * 8 + e];
    const float* src = A + b * (size_t)K + k;
    float4 v0 = ((const float4*)src)[0];
    float4 v1 = ((const float4*)src)[1];
    u16x8 r;
    r[0] = f2bf(g * v0.x); r[1] = f2bf(g * v0.y); r[2] = f2bf(g * v0.z); r[3] = f2bf(g * v0.w);
    r[4] = f2bf(g * v1.x); r[5] = f2bf(g * v1.y); r[6] = f2bf(g * v1.z); r[7] = f2bf(g * v1.w);
    *(u16x8*)(out + idx) = r;
}

__global__ void make_atilde_bf16(const u16* __restrict__ A, const float* __restrict__ gate,
                                 u16* __restrict__ out, int log2K) {
    const size_t idx = ((size_t)blockIdx.x * 256 + threadIdx.x) * 8;
    const int K = 1 << log2K;
    const size_t b = idx >> (log2K + 3);
    const int rem = (int)(idx - (b << (log2K + 3)));
    const int e = rem >> log2K;
    const int k = rem & (K - 1);
    const float g = gate[b * 8 + e];
    u16x8 a = *(const u16x8*)(A + b * (size_t)K + k);
    u16x8 r;
    #pragma unroll
    for (int j = 0; j < 8; ++j) r[j] = f2bf(g * bf2f(a[j]));
    *(u16x8*)(out + idx) = r;
}

// ---------------- 256x256 split-K GEMM, single-barrier 2-deep frame -----------
// P[s][b][n] = sum_{kt in seg s} At-slice · Bw-slice (raw f32 partials).
// 512 threads = 8 waves (2M x 4N); per-wave output 128x64; BK=64.
// LDS 128 KB: buf x { A 2x[128x64] | B 2x[128x64] }, XOR-swizzled 128B rows.
// Frame t (BUF static): STAGE B(t+1)@top, A(t+1) after q0 reads; reads+MFMA
// free-run; ONE {vmcnt(0); s_barrier} per k-tile. Issue->drain window ~= one
// full k-tile (~3.5k cyc) >> HBM latency, so the drain is non-binding.
__global__ __launch_bounds__(512, 2)
void moe_gemm_1b(const u16* __restrict__ At, const u16* __restrict__ Bw,
                 float* __restrict__ P,
                 int N, int K, int Ktot, int log2nk, int kts, int bxbits) {
    __shared__ char lds[2][65536];

    const int tid  = threadIdx.x;
    const int lane = tid & 63;
    const int wave = tid >> 6;
    const int wm   = wave >> 2;          // 0..1  (M half)
    const int wn   = wave & 3;           // 0..3  (N quarter)
    const int fr   = lane & 15;
    const int fg   = lane >> 4;
    const int swz  = (fr & 7) << 4;

    // XCD-chunked swizzle over exactly 256 blocks (32 per XCD)
    const int bid  = blockIdx.x;
    const int wgid = (bid & 7) * 32 + (bid >> 3);
    const int bx   = wgid & ((1 << bxbits) - 1);
    const int by   = (wgid >> bxbits) & 31;
    const int s    = wgid >> (bxbits + 5);
    const int m0   = by * 256;
    const int n0   = bx * 256;

    // per-thread staging offsets
    int rowA[2], rowB[2], ldso[2];
    #pragma unroll
    for (int it = 0; it < 2; ++it) {
        const int o  = (it * 8 + wave) * 1024 + lane * 16;
        const int r  = o >> 7;                      // 128B per row
        const int cb = (o & 127) ^ ((r & 7) << 4);  // inverse-swizzled src col
        rowA[it] = r * (Ktot * 2) + cb;
        rowB[it] = r * (K * 2) + cb;
        ldso[it] = o;
    }

    const char* Ab0 = (const char*)(At + (size_t)m0 * Ktot);
    const char* Ab1 = Ab0 + (size_t)128 * Ktot * 2;
    const char* Bb0 = (const char*)(Bw + (size_t)n0 * K);
    const char* Bb1 = Bb0 + (size_t)128 * K * 2;
    const size_t Best = (size_t)N * K * 2;
    const int nkm = (1 << log2nk) - 1;
    const int kt0 = s * kts;

#define STAGE_A(BUF, KTG) do { \
    const char* _a0 = Ab0 + (size_t)(KTG) * 128; \
    const char* _a1 = Ab1 + (size_t)(KTG) * 128; \
    char* _l = lds[BUF]; \
    gload16(_a0 + rowA[0], _l + ldso[0]); \
    gload16(_a0 + rowA[1], _l + ldso[1]); \
    gload16(_a1 + rowA[0], _l + 16384 + ldso[0]); \
    gload16(_a1 + rowA[1], _l + 16384 + ldso[1]); \
} while (0)

#define STAGE_B(BUF, KTG) do { \
    const int _kg = (KTG); \
    const size_t _bo = (size_t)(_kg >> log2nk) * Best + (size_t)(_kg & nkm) * 128; \
    char* _l = lds[BUF] + 32768; \
    gload16(Bb0 + _bo + rowB[0], _l + ldso[0]); \
    gload16(Bb0 + _bo + rowB[1], _l + ldso[1]); \
    gload16(Bb1 + _bo + rowB[0], _l + 16384 + ldso[0]); \
    gload16(Bb1 + _bo + rowB[1], _l + 16384 + ldso[1]); \
} while (0)

    f32x4 acc[8][4];
    #pragma unroll
    for (int i = 0; i < 8; ++i)
        #pragma unroll
        for (int j = 0; j < 4; ++j) acc[i][j] = f32x4{0.f, 0.f, 0.f, 0.f};

    bf16x8 af[2][4], bfA[2][2], bfB[2][2];

    // loop-invariant LDS read bases (per buffer)
    const char* aB[2], * bB[2];
    #pragma unroll
    for (int u = 0; u < 2; ++u) {
        aB[u] = lds[u] + wm * 16384 + fr * 128;
        bB[u] = lds[u] + 32768 + (wn >> 1) * 16384 + ((wn & 1) * 64 + fr) * 128;
    }
    const int k0 = (fg * 16) ^ swz;
    const int k1 = (64 + fg * 16) ^ swz;

    // prologue: A(0)+B(0) -> buf0; drain; barrier
    STAGE_A(0, kt0);
    STAGE_B(0, kt0);
    __builtin_amdgcn_sched_barrier(0);
    asm volatile("s_waitcnt vmcnt(0)" ::: "memory");
    __builtin_amdgcn_s_barrier();
    __builtin_amdgcn_sched_barrier(0);

#define KTILE(BUF, T) do { \
    const int _t = (T); \
    if (_t + 1 < kts) STAGE_B((BUF) ^ 1, kt0 + _t + 1); \
    _Pragma("unroll") for (int i = 0; i < 4; ++i) { \
        af[0][i] = *(const bf16x8*)(aB[BUF] + i * 2048 + k0); \
        af[1][i] = *(const bf16x8*)(aB[BUF] + i * 2048 + k1); } \
    _Pragma("unroll") for (int j = 0; j < 2; ++j) { \
        bfA[0][j] = *(const bf16x8*)(bB[BUF] + j * 2048 + k0); \
        bfA[1][j] = *(const bf16x8*)(bB[BUF] + j * 2048 + k1); } \
    if (_t + 1 < kts) STAGE_A((BUF) ^ 1, kt0 + _t + 1); \
    __builtin_amdgcn_s_setprio(1); \
    _Pragma("unroll") for (int i = 0; i < 4; ++i) \
    _Pragma("unroll") for (int j = 0; j < 2; ++j) { \
        acc[i][j] = __builtin_amdgcn_mfma_f32_16x16x32_bf16(af[0][i], bfA[0][j], acc[i][j], 0, 0, 0); \
        acc[i][j] = __builtin_amdgcn_mfma_f32_16x16x32_bf16(af[1][i], bfA[1][j], acc[i][j], 0, 0, 0); } \
    __builtin_amdgcn_s_setprio(0); \
    _Pragma("unroll") for (int j = 0; j < 2; ++j) { \
        bfB[0][j] = *(const bf16x8*)(bB[BUF] + (2 + j) * 2048 + k0); \
        bfB[1][j] = *(const bf16x8*)(bB[BUF] + (2 + j) * 2048 + k1); } \
    __builtin_amdgcn_s_setprio(1); \
    _Pragma("unroll") for (int i = 0; i < 4; ++i) \
    _Pragma("unroll") for (int j = 0; j < 2; ++j) { \
        acc[i][2 + j] = __builtin_amdgcn_mfma_f32_16x16x32_bf16(af[0][i], bfB[0][j], acc[i][2 + j], 0, 0, 0); \
        acc[i][2 + j] = __builtin_amdgcn_mfma_f32_16x16x32_bf16(af[1][i], bfB[1][j], acc[i][2 + j], 0, 0, 0); } \
    __builtin_amdgcn_s_setprio(0); \
    _Pragma("unroll") for (int i = 0; i < 4; ++i) { \
        af[0][i] = *(const bf16x8*)(aB[BUF] + (4 + i) * 2048 + k0); \
        af[1][i] = *(const bf16x8*)(aB[BUF] + (4 + i) * 2048 + k1); } \
    __builtin_amdgcn_s_setprio(1); \
    _Pragma("unroll") for (int i = 0; i < 4; ++i) \
    _Pragma("unroll") for (int j = 0; j < 2; ++j) { \
        acc[4 + i][2 + j] = __builtin_amdgcn_mfma_f32_16x16x32_bf16(af[0][i], bfB[0][j], acc[4 + i][2 + j], 0, 0, 0); \
        acc[4 + i][2 + j] = __builtin_amdgcn_mfma_f32_16x16x32_bf16(af[1][i], bfB[1][j], acc[4 + i][2 + j], 0, 0, 0); } \
    _Pragma("unroll") for (int i = 0; i < 4; ++i) \
    _Pragma("unroll") for (int j = 0; j < 2; ++j) { \
        acc[4 + i][j] = __builtin_amdgcn_mfma_f32_16x16x32_bf16(af[0][i], bfA[0][j], acc[4 + i][j], 0, 0, 0); \
        acc[4 + i][j] = __builtin_amdgcn_mfma_f32_16x16x32_bf16(af[1][i], bfA[1][j], acc[4 + i][j], 0, 0, 0); } \
    __builtin_amdgcn_s_setprio(0); \
    __builtin_amdgcn_sched_barrier(0); \
    asm volatile("s_waitcnt vmcnt(0)" ::: "memory"); \
    __builtin_amdgcn_s_barrier(); \
    __builtin_amdgcn_sched_barrier(0); \
} while (0)

    for (int t = 0; t < kts; t += 2) {   // kts is even (32/64)
        KTILE(0, t);
        KTILE(1, t + 1);
    }

    // epilogue: raw f32 partial store
    float* Pb = P + ((size_t)s * 8192 + m0 + wm * 128) * N + (n0 + wn * 64);
    #pragma unroll
    for (int mi = 0; mi < 8; ++mi)
        #pragma unroll
        for (int j = 0; j < 4; ++j) {
            const int r = mi * 16 + fg * 4 + j;
            #pragma unroll
            for (int ni = 0; ni < 4; ++ni)
                Pb[(size_t)r * N + ni * 16 + fr] = acc[mi][ni][j];
        }
#undef KTILE
#undef STAGE_A
#undef STAGE_B
}

// ---------------- split-K reduce: sum partials + gate-weighted bias + act -----
template<int S, bool ELU_ACT, bool OUT_BF16>
__global__ void moe_reduce(const float* __restrict__ P,
                           const float* __restrict__ gate,
                           const float* __restrict__ bias,
                           void* __restrict__ outp,
                           int log2N, int n4total) {
    const int stride = gridDim.x * blockDim.x;
    const size_t MN = ((size_t)n4total) * 4;
    for (int i = blockIdx.x * blockDim.x + threadIdx.x; i < n4total; i += stride) {
        const size_t el = (size_t)i * 4;
        const size_t b = el >> log2N;
        const int n = (int)(el & ((1 << log2N) - 1));
        float4 v = ((const float4*)P)[i];
        #pragma unroll
        for (int s = 1; s < S; ++s) {
            float4 p = *(const float4*)(P + (size_t)s * MN + el);
            v.x += p.x; v.y += p.y; v.z += p.z; v.w += p.w;
        }
        #pragma unroll
        for (int e = 0; e < 8; ++e) {
            const float g = gate[b * 8 + e];
            float4 bb = *(const float4*)(bias + ((size_t)e << log2N) + n);
            v.x += g * bb.x; v.y += g * bb.y; v.z += g * bb.z; v.w += g * bb.w;
        }
        if (ELU_ACT) {
            v.x = v.x > 0.f ? v.x : expm1f(v.x);
            v.y = v.y > 0.f ? v.y : expm1f(v.y);
            v.z = v.z > 0.f ? v.z : expm1f(v.z);
            v.w = v.w > 0.f ? v.w : expm1f(v.w);
        }
        if (OUT_BF16) {
            ushort4 o; o.x = f2bf(v.x); o.y = f2bf(v.y); o.z = f2bf(v.z); o.w = f2bf(v.w);
            ((ushort4*)outp)[i] = o;
        } else {
            ((float4*)outp)[i] = v;
        }
    }
}

// ---- fused: reduce(S=2, bias b2, ELU) + atilde (gate-scale, 8 expert copies) -
// P: [2][8192][1024] f32; At: [8192][8*1024] bf16. Thread = 8 h of one row.
__global__ void reduce_atilde2(const float* __restrict__ P,
                               const float* __restrict__ gate,
                               const float* __restrict__ bias,
                               u16* __restrict__ At) {
    const int idx = blockIdx.x * 256 + threadIdx.x;   // 8192*128 total
    const int h = (idx & 127) * 8;
    const size_t b = idx >> 7;
    const size_t MH = (size_t)8192 * 1024;
    const float* p = P + b * 1024 + h;
    float4 v0 = ((const float4*)p)[0];
    float4 v1 = ((const float4*)p)[1];
    {
        const float* p1 = p + MH;
        float4 a0 = ((const float4*)p1)[0], a1 = ((const float4*)p1)[1];
        v0.x += a0.x; v0.y += a0.y; v0.z += a0.z; v0.w += a0.w;
        v1.x += a1.x; v1.y += a1.y; v1.z += a1.z; v1.w += a1.w;
    }
    float4 g0 = *(const float4*)&gate[b * 8];
    float4 g1 = *(const float4*)&gate[b * 8 + 4];
    float gg[8] = {g0.x, g0.y, g0.z, g0.w, g1.x, g1.y, g1.z, g1.w};
    #pragma unroll
    for (int e = 0; e < 8; ++e) {
        const float* bb = bias + e * 1024 + h;
        float4 b0 = ((const float4*)bb)[0], b1 = ((const float4*)bb)[1];
        v0.x += gg[e] * b0.x; v0.y += gg[e] * b0.y; v0.z += gg[e] * b0.z; v0.w += gg[e] * b0.w;
        v1.x += gg[e] * b1.x; v1.y += gg[e] * b1.y; v1.z += gg[e] * b1.z; v1.w += gg[e] * b1.w;
    }
    float m[8] = {v0.x, v0.y, v0.z, v0.w, v1.x, v1.y, v1.z, v1.w};
    #pragma unroll
    for (int j = 0; j < 8; ++j) m[j] = m[j] > 0.f ? m[j] : expm1f(m[j]);
    u16* o = At + b * 8192 + h;
    #pragma unroll
    for (int e = 0; e < 8; ++e) {
        u16x8 r;
        #pragma unroll
        for (int j = 0; j < 8; ++j) r[j] = f2bf(gg[e] * m[j]);
        *(u16x8*)(o + e * 1024) = r;
    }
}

// ---------------- launcher ----------------------------------------------------
extern "C" void kernel_launch(void* const* d_in, const int* in_sizes, int n_in,
                              void* d_out, int out_size, void* d_ws, size_t ws_size,
                              hipStream_t stream) {
    const float* X  = (const float*)d_in[0];   // [8192,512]
    const float* W  = (const float*)d_in[1];   // [8192,8]
    const float* W1 = (const float*)d_in[2];   // [8,1024,512]
    const float* b1 = (const float*)d_in[3];   // [8,1024]
    const float* W2 = (const float*)d_in[4];   // [8,1024,1024]
    const float* b2 = (const float*)d_in[5];   // [8,1024]
    const float* W3 = (const float*)d_in[6];   // [8,512,1024]
    const float* b3 = (const float*)d_in[7];   // [8,512]
    float* out = (float*)d_out;

    char* ws = (char*)d_ws;
    u16* W1b  = (u16*)ws;  ws += (size_t)8 * 1024 * 512 * 2;     //  8.4 MB
    u16* W2b  = (u16*)ws;  ws += (size_t)8 * 1024 * 1024 * 2;    // 16.8 MB
    u16* W3b  = (u16*)ws;  ws += (size_t)8 * 512 * 1024 * 2;     //  8.4 MB
    u16* mid1 = (u16*)ws;  ws += (size_t)8192 * 1024 * 2;        // 16.8 MB
    u16* mid2 = (u16*)ws;  ws += (size_t)8192 * 1024 * 2;        // 16.8 MB (unused)
    u16* At1  = (u16*)ws;  ws += (size_t)8192 * 4096 * 2;        //   67 MB
    u16* At2  = (u16*)ws;  ws += (size_t)8192 * 8192 * 2;        //  134 MB
    (void)mid2;

    // partial slabs reuse dead regions:
    float* P1 = (float*)At2;   // L1 gemm -> L1 reduce (before atilde2 writes At2)
    float* P2 = (float*)At1;   // L2 gemm -> fused reduce2/atilde3 (At1 dead)
    float* P3 = (float*)At1;   // L3 gemm -> L3 reduce (P2 consumed)

    // weight converts
    cvt_f32_bf16<<<4096, 256, 0, stream>>>(W1, W1b, 4194304 / 4);
    cvt_f32_bf16<<<8192, 256, 0, stream>>>(W2, W2b, 8388608 / 4);
    cvt_f32_bf16<<<4096, 256, 0, stream>>>(W3, W3b, 4194304 / 4);

    dim3 blk(256);

    // L1: At1 = gate ⊙ X [8192,4096]; S=2 GEMM; reduce -> mid1 (ELU bf16)
    make_atilde_f32<<<16384, blk, 0, stream>>>(X, W, At1, 9);
    moe_gemm_1b<<<256, 512, 0, stream>>>(At1, W1b, P1, 1024, 512, 4096, 3, 32, 2);
    moe_reduce<2, true, true><<<2048, blk, 0, stream>>>(P1, W, b1, (void*)mid1, 10, 8192 * 1024 / 4);

    // L2: At2 = gate ⊙ mid1 [8192,8192]; S=2 GEMM; fused reduce+atilde -> At3(=At2)
    make_atilde_bf16<<<32768, blk, 0, stream>>>(mid1, W, At2, 10);
    moe_gemm_1b<<<256, 512, 0, stream>>>(At2, W2b, P2, 1024, 1024, 8192, 4, 64, 2);
    reduce_atilde2<<<4096, blk, 0, stream>>>(P2, W, b2, At2);

    // L3: GEMM over At2; S=4; reduce -> out (f32)
    moe_gemm_1b<<<256, 512, 0, stream>>>(At2, W3b, P3, 512, 1024, 8192, 4, 32, 1);
    moe_reduce<4, false, false><<<2048, blk, 0, stream>>>(P3, W, b3, (void*)out, 9, 8192 * 512 / 4);
}

// Round 9
// 354.294 us; speedup vs baseline: 10.5837x; 1.0583x over previous
//
#include <hip/hip_runtime.h>
#include <hip/hip_bf16.h>
#include <cstdint>
#include <cstddef>

typedef __attribute__((ext_vector_type(8))) short bf16x8;
typedef __attribute__((ext_vector_type(8))) unsigned short u16x8;
typedef __attribute__((ext_vector_type(4))) float f32x4;
typedef unsigned short u16;

__device__ __forceinline__ u16 f2bf(float f) {
    unsigned int u = __float_as_uint(f);
    u += 0x7fffu + ((u >> 16) & 1u);   // RNE
    return (u16)(u >> 16);
}
__device__ __forceinline__ float bf2f(u16 u) {
    return __uint_as_float(((unsigned int)u) << 16);
}

__device__ __forceinline__ void gload16(const void* g, void* l) {
    __builtin_amdgcn_global_load_lds((const __attribute__((address_space(1))) void*)g,
                                     (__attribute__((address_space(3))) void*)l,
                                     16, 0, 0);
}

// ---------------- f32 -> bf16 convert (weights) -------------------------------
__global__ void cvt_f32_bf16(const float* __restrict__ in, u16* __restrict__ out, int n4) {
    int i = blockIdx.x * blockDim.x + threadIdx.x;
    if (i < n4) {
        float4 v = ((const float4*)in)[i];
        ushort4 o;
        o.x = f2bf(v.x); o.y = f2bf(v.y); o.z = f2bf(v.z); o.w = f2bf(v.w);
        ((ushort4*)out)[i] = o;
    }
}

// ---------------- gated-A materialization: At[b, e*K+k] = g[b,e]*X[b,k] -------
__global__ void make_atilde_f32(const float* __restrict__ A, const float* __restrict__ gate,
                                u16* __restrict__ out, int log2K) {
    const size_t idx = ((size_t)blockIdx.x * 256 + threadIdx.x) * 8;
    const int K = 1 << log2K;
    const size_t b = idx >> (log2K + 3);
    const int rem = (int)(idx - (b << (log2K + 3)));
    const int e = rem >> log2K;
    const int k = rem & (K - 1);
    const float g = gate[b * 8 + e];
    const float* src = A + b * (size_t)K + k;
    float4 v0 = ((const float4*)src)[0];
    float4 v1 = ((const float4*)src)[1];
    u16x8 r;
    r[0] = f2bf(g * v0.x); r[1] = f2bf(g * v0.y); r[2] = f2bf(g * v0.z); r[3] = f2bf(g * v0.w);
    r[4] = f2bf(g * v1.x); r[5] = f2bf(g * v1.y); r[6] = f2bf(g * v1.z); r[7] = f2bf(g * v1.w);
    *(u16x8*)(out + idx) = r;
}

// ---------------- L1 fused GEMM: 128x128, S=1, epilogue -> At2 ----------------
// acc = At1-tile · W1-slice over full Ktot; epilogue: v = acc + sum_e g*b1;
// ELU; write 8 gated bf16 copies into At2[b][e*1024 + n].
__global__ __launch_bounds__(256, 4)
void moe_gemm_l1f(const u16* __restrict__ At,
                  const u16* __restrict__ Bw,
                  const float* __restrict__ gate,
                  const float* __restrict__ bias,
                  u16* __restrict__ At2out,
                  int N, int K, int Ktot, int log2nk, int kts) {
    constexpr int BM = 128, BN = 128, BK = 64;
    __shared__ u16 As[BM * BK];    // 16 KB, swizzled 128B rows
    __shared__ u16 Bs[BN * BK];    // 16 KB

    const int tid  = threadIdx.x;
    const int lane = tid & 63;
    const int wave = tid >> 6;
    const int wr = wave >> 1, wc = wave & 1;
    const int fr = lane & 15;
    const int fg = lane >> 4;

    // XCD swizzle: bid&7=xcd, idx 0..63 -> (by 0..7 within xcd, bx 0..7)
    const int bid = blockIdx.x;
    const int xcd = bid & 7, idx = bid >> 3;
    const int bx  = idx & 7;
    const int by  = xcd * 8 + (idx >> 3);
    const int m0  = by * BM;
    const int n0  = bx * BN;

    int rowoffA[4], rowoffB[4], ldsoff[4];
    #pragma unroll
    for (int it = 0; it < 4; ++it) {
        const int c   = it * 4 + wave;
        const int L   = c * 1024 + lane * 16;
        const int row = L >> 7;
        const int cb  = (L & 127) ^ ((row & 7) << 4);
        rowoffA[it] = row * (Ktot * 2) + cb;
        rowoffB[it] = row * (K * 2) + cb;
        ldsoff[it]  = c * 1024;
    }

    const char* Abase = (const char*)(At + (size_t)m0 * Ktot);
    const char* Bbase = (const char*)(Bw + (size_t)n0 * K);
    const size_t Bestride = (size_t)N * K * 2;
    const int swz    = (fr & 7) << 4;
    const int nkmask = (1 << log2nk) - 1;

    f32x4 acc[4][4];
    #pragma unroll
    for (int a = 0; a < 4; ++a)
        #pragma unroll
        for (int b = 0; b < 4; ++b) acc[a][b] = f32x4{0.f, 0.f, 0.f, 0.f};

    for (int kt = 0; kt < kts; ++kt) {
        __syncthreads();
        const char* Ab = Abase + kt * 128;
        const char* Bb = Bbase + (size_t)(kt >> log2nk) * Bestride + (kt & nkmask) * 128;
        #pragma unroll
        for (int it = 0; it < 4; ++it) {
            gload16(Ab + rowoffA[it], (char*)As + ldsoff[it]);
            gload16(Bb + rowoffB[it], (char*)Bs + ldsoff[it]);
        }
        __syncthreads();

        #pragma unroll
        for (int kk = 0; kk < 2; ++kk) {
            const int kb = kk * 64 + fg * 16;
            bf16x8 af[4], bfr[4];
            #pragma unroll
            for (int mi = 0; mi < 4; ++mi) {
                const int r  = wr * 64 + mi * 16 + fr;
                af[mi]  = *(const bf16x8*)((const char*)As + r * 128 + (kb ^ swz));
                const int cc = wc * 64 + mi * 16 + fr;
                bfr[mi] = *(const bf16x8*)((const char*)Bs + cc * 128 + (kb ^ swz));
            }
            #pragma unroll
            for (int mi = 0; mi < 4; ++mi)
                #pragma unroll
                for (int ni = 0; ni < 4; ++ni)
                    acc[mi][ni] = __builtin_amdgcn_mfma_f32_16x16x32_bf16(
                        af[mi], bfr[ni], acc[mi][ni], 0, 0, 0);
        }
    }

    // ---- fused epilogue: bias + ELU + 8 gated expert copies -> At2out -------
    __syncthreads();                 // hot-loop LDS reads done; reuse As/Bs
    float* WsL   = (float*)As;       // [128][8] gates
    float* BiasL = (float*)Bs;       // [8][128] bias tile
    {
        const int j = tid * 4;
        *(float4*)&WsL[j]   = *(const float4*)&gate[(size_t)(m0 + (j >> 3)) * 8 + (j & 7)];
        *(float4*)&BiasL[j] = *(const float4*)&bias[(size_t)(j >> 7) * N + n0 + (j & 127)];
    }
    __syncthreads();

    float bias8[4][8];
    #pragma unroll
    for (int ni = 0; ni < 4; ++ni)
        #pragma unroll
        for (int e = 0; e < 8; ++e)
            bias8[ni][e] = BiasL[e * BN + wc * 64 + ni * 16 + fr];

    #pragma unroll
    for (int mi = 0; mi < 4; ++mi) {
        #pragma unroll
        for (int j = 0; j < 4; ++j) {
            const int r = wr * 64 + mi * 16 + fg * 4 + j;
            float g8[8];
            #pragma unroll
            for (int e = 0; e < 8; ++e) g8[e] = WsL[r * 8 + e];
            #pragma unroll
            for (int ni = 0; ni < 4; ++ni) {
                float v = acc[mi][ni][j];
                #pragma unroll
                for (int e = 0; e < 8; ++e) v += g8[e] * bias8[ni][e];
                v = v > 0.f ? v : expm1f(v);
                const int cl = wc * 64 + ni * 16 + fr;
                const size_t base = (size_t)(m0 + r) * 8192 + n0 + cl;
                #pragma unroll
                for (int e = 0; e < 8; ++e)
                    At2out[base + e * 1024] = f2bf(g8[e] * v);
            }
        }
    }
}

// ---------------- 256x256 split-K GEMM, 2-barrier free-run frame (V7) ---------
__global__ __launch_bounds__(512, 2)
void moe_gemm_2b(const u16* __restrict__ At, const u16* __restrict__ Bw,
                 float* __restrict__ P,
                 int N, int K, int Ktot, int log2nk, int kts, int bxbits) {
    __shared__ char lds[2][65536];

    const int tid  = threadIdx.x;
    const int lane = tid & 63;
    const int wave = tid >> 6;
    const int wm   = wave >> 2;
    const int wn   = wave & 3;
    const int fr   = lane & 15;
    const int fg   = lane >> 4;
    const int swz  = (fr & 7) << 4;

    const int bid  = blockIdx.x;
    const int wgid = (bid & 7) * 32 + (bid >> 3);
    const int bx   = wgid & ((1 << bxbits) - 1);
    const int by   = (wgid >> bxbits) & 31;
    const int s    = wgid >> (bxbits + 5);
    const int m0   = by * 256;
    const int n0   = bx * 256;

    int rowA[2], rowB[2], ldso[2];
    #pragma unroll
    for (int it = 0; it < 2; ++it) {
        const int o  = (it * 8 + wave) * 1024 + lane * 16;
        const int r  = o >> 7;
        const int cb = (o & 127) ^ ((r & 7) << 4);
        rowA[it] = r * (Ktot * 2) + cb;
        rowB[it] = r * (K * 2) + cb;
        ldso[it] = o;
    }

    const char* Ab0 = (const char*)(At + (size_t)m0 * Ktot);
    const char* Ab1 = Ab0 + (size_t)128 * Ktot * 2;
    const char* Bb0 = (const char*)(Bw + (size_t)n0 * K);
    const char* Bb1 = Bb0 + (size_t)128 * K * 2;
    const size_t Best = (size_t)N * K * 2;
    const int nkm = (1 << log2nk) - 1;
    const int kt0 = s * kts;

#define STAGE_A(BUF, KTG) do { \
    const char* _a0 = Ab0 + (size_t)(KTG) * 128; \
    const char* _a1 = Ab1 + (size_t)(KTG) * 128; \
    char* _l = lds[BUF]; \
    gload16(_a0 + rowA[0], _l + ldso[0]); \
    gload16(_a0 + rowA[1], _l + ldso[1]); \
    gload16(_a1 + rowA[0], _l + 16384 + ldso[0]); \
    gload16(_a1 + rowA[1], _l + 16384 + ldso[1]); \
} while (0)

#define STAGE_B(BUF, KTG) do { \
    const int _kg = (KTG); \
    const size_t _bo = (size_t)(_kg >> log2nk) * Best + (size_t)(_kg & nkm) * 128; \
    char* _l = lds[BUF] + 32768; \
    gload16(Bb0 + _bo + rowB[0], _l + ldso[0]); \
    gload16(Bb0 + _bo + rowB[1], _l + ldso[1]); \
    gload16(Bb1 + _bo + rowB[0], _l + 16384 + ldso[0]); \
    gload16(Bb1 + _bo + rowB[1], _l + 16384 + ldso[1]); \
} while (0)

    f32x4 acc[8][4];
    #pragma unroll
    for (int i = 0; i < 8; ++i)
        #pragma unroll
        for (int j = 0; j < 4; ++j) acc[i][j] = f32x4{0.f, 0.f, 0.f, 0.f};

    bf16x8 af[2][4], bfA[2][2], bfB[2][2];

    STAGE_A(0, kt0);
    STAGE_B(0, kt0);
    STAGE_A(1, kt0 + 1);
    __builtin_amdgcn_sched_barrier(0);
    asm volatile("s_waitcnt vmcnt(4)" ::: "memory");
    __builtin_amdgcn_s_barrier();
    __builtin_amdgcn_sched_barrier(0);

    for (int t = 0; t < kts; ++t) {
        const int BUF = t & 1;
        const char* _abase = lds[BUF] + wm * 16384 + fr * 128;
        const char* _bbase = lds[BUF] + 32768 + (wn >> 1) * 16384 + ((wn & 1) * 64 + fr) * 128;
        const int k0 = (fg * 16) ^ swz;
        const int k1 = (64 + fg * 16) ^ swz;

        if (t + 1 < kts) STAGE_B(BUF ^ 1, kt0 + t + 1);

        #pragma unroll
        for (int i = 0; i < 4; ++i) {
            af[0][i] = *(const bf16x8*)(_abase + i * 2048 + k0);
            af[1][i] = *(const bf16x8*)(_abase + i * 2048 + k1);
        }
        #pragma unroll
        for (int j = 0; j < 2; ++j) {
            bfA[0][j] = *(const bf16x8*)(_bbase + j * 2048 + k0);
            bfA[1][j] = *(const bf16x8*)(_bbase + j * 2048 + k1);
        }
        __builtin_amdgcn_s_setprio(1);
        #pragma unroll
        for (int i = 0; i < 4; ++i)
            #pragma unroll
            for (int j = 0; j < 2; ++j) {
                acc[i][j] = __builtin_amdgcn_mfma_f32_16x16x32_bf16(af[0][i], bfA[0][j], acc[i][j], 0, 0, 0);
                acc[i][j] = __builtin_amdgcn_mfma_f32_16x16x32_bf16(af[1][i], bfA[1][j], acc[i][j], 0, 0, 0);
            }
        __builtin_amdgcn_s_setprio(0);

        #pragma unroll
        for (int j = 0; j < 2; ++j) {
            bfB[0][j] = *(const bf16x8*)(_bbase + (2 + j) * 2048 + k0);
            bfB[1][j] = *(const bf16x8*)(_bbase + (2 + j) * 2048 + k1);
        }
        __builtin_amdgcn_s_setprio(1);
        #pragma unroll
        for (int i = 0; i < 4; ++i)
            #pragma unroll
            for (int j = 0; j < 2; ++j) {
                acc[i][2 + j] = __builtin_amdgcn_mfma_f32_16x16x32_bf16(af[0][i], bfB[0][j], acc[i][2 + j], 0, 0, 0);
                acc[i][2 + j] = __builtin_amdgcn_mfma_f32_16x16x32_bf16(af[1][i], bfB[1][j], acc[i][2 + j], 0, 0, 0);
            }
        __builtin_amdgcn_s_setprio(0);

        #pragma unroll
        for (int i = 0; i < 4; ++i) {
            af[0][i] = *(const bf16x8*)(_abase + (4 + i) * 2048 + k0);
            af[1][i] = *(const bf16x8*)(_abase + (4 + i) * 2048 + k1);
        }
        __builtin_amdgcn_s_setprio(1);
        #pragma unroll
        for (int i = 0; i < 4; ++i)
            #pragma unroll
            for (int j = 0; j < 2; ++j) {
                acc[4 + i][2 + j] = __builtin_amdgcn_mfma_f32_16x16x32_bf16(af[0][i], bfB[0][j], acc[4 + i][2 + j], 0, 0, 0);
                acc[4 + i][2 + j] = __builtin_amdgcn_mfma_f32_16x16x32_bf16(af[1][i], bfB[1][j], acc[4 + i][2 + j], 0, 0, 0);
            }
        __builtin_amdgcn_s_setprio(0);

        __builtin_amdgcn_sched_barrier(0);
        __builtin_amdgcn_s_barrier();
        __builtin_amdgcn_sched_barrier(0);

        if (t + 2 < kts) STAGE_A(BUF, kt0 + t + 2);

        __builtin_amdgcn_s_setprio(1);
        #pragma unroll
        for (int i = 0; i < 4; ++i)
            #pragma unroll
            for (int j = 0; j < 2; ++j) {
                acc[4 + i][j] = __builtin_amdgcn_mfma_f32_16x16x32_bf16(af[0][i], bfA[0][j], acc[4 + i][j], 0, 0, 0);
                acc[4 + i][j] = __builtin_amdgcn_mfma_f32_16x16x32_bf16(af[1][i], bfA[1][j], acc[4 + i][j], 0, 0, 0);
            }
        __builtin_amdgcn_s_setprio(0);

        __builtin_amdgcn_sched_barrier(0);
        if (t + 2 < kts) {
            asm volatile("s_waitcnt vmcnt(4)" ::: "memory");
        } else {
            asm volatile("s_waitcnt vmcnt(0)" ::: "memory");
        }
        __builtin_amdgcn_s_barrier();
        __builtin_amdgcn_sched_barrier(0);
    }

    float* Pb = P + ((size_t)s * 8192 + m0 + wm * 128) * N + (n0 + wn * 64);
    #pragma unroll
    for (int mi = 0; mi < 8; ++mi)
        #pragma unroll
        for (int j = 0; j < 4; ++j) {
            const int r = mi * 16 + fg * 4 + j;
            #pragma unroll
            for (int ni = 0; ni < 4; ++ni)
                Pb[(size_t)r * N + ni * 16 + fr] = acc[mi][ni][j];
        }
#undef STAGE_A
#undef STAGE_B
}

// ---------------- split-K reduce: sum partials + gate-weighted bias + act -----
template<int S, bool ELU_ACT, bool OUT_BF16>
__global__ void moe_reduce(const float* __restrict__ P,
                           const float* __restrict__ gate,
                           const float* __restrict__ bias,
                           void* __restrict__ outp,
                           int log2N, int n4total) {
    const int stride = gridDim.x * blockDim.x;
    const size_t MN = ((size_t)n4total) * 4;
    for (int i = blockIdx.x * blockDim.x + threadIdx.x; i < n4total; i += stride) {
        const size_t el = (size_t)i * 4;
        const size_t b = el >> log2N;
        const int n = (int)(el & ((1 << log2N) - 1));
        float4 v = ((const float4*)P)[i];
        #pragma unroll
        for (int s = 1; s < S; ++s) {
            float4 p = *(const float4*)(P + (size_t)s * MN + el);
            v.x += p.x; v.y += p.y; v.z += p.z; v.w += p.w;
        }
        #pragma unroll
        for (int e = 0; e < 8; ++e) {
            const float g = gate[b * 8 + e];
            float4 bb = *(const float4*)(bias + ((size_t)e << log2N) + n);
            v.x += g * bb.x; v.y += g * bb.y; v.z += g * bb.z; v.w += g * bb.w;
        }
        if (ELU_ACT) {
            v.x = v.x > 0.f ? v.x : expm1f(v.x);
            v.y = v.y > 0.f ? v.y : expm1f(v.y);
            v.z = v.z > 0.f ? v.z : expm1f(v.z);
            v.w = v.w > 0.f ? v.w : expm1f(v.w);
        }
        if (OUT_BF16) {
            ushort4 o; o.x = f2bf(v.x); o.y = f2bf(v.y); o.z = f2bf(v.z); o.w = f2bf(v.w);
            ((ushort4*)outp)[i] = o;
        } else {
            ((float4*)outp)[i] = v;
        }
    }
}

// ---- fused: reduce(S=2, bias b2, ELU) + atilde (gate-scale, 8 expert copies) -
__global__ void reduce_atilde2(const float* __restrict__ P,
                               const float* __restrict__ gate,
                               const float* __restrict__ bias,
                               u16* __restrict__ At) {
    const int idx = blockIdx.x * 256 + threadIdx.x;   // 8192*128 total
    const int h = (idx & 127) * 8;
    const size_t b = idx >> 7;
    const size_t MH = (size_t)8192 * 1024;
    const float* p = P + b * 1024 + h;
    float4 v0 = ((const float4*)p)[0];
    float4 v1 = ((const float4*)p)[1];
    {
        const float* p1 = p + MH;
        float4 a0 = ((const float4*)p1)[0], a1 = ((const float4*)p1)[1];
        v0.x += a0.x; v0.y += a0.y; v0.z += a0.z; v0.w += a0.w;
        v1.x += a1.x; v1.y += a1.y; v1.z += a1.z; v1.w += a1.w;
    }
    float4 g0 = *(const float4*)&gate[b * 8];
    float4 g1 = *(const float4*)&gate[b * 8 + 4];
    float gg[8] = {g0.x, g0.y, g0.z, g0.w, g1.x, g1.y, g1.z, g1.w};
    #pragma unroll
    for (int e = 0; e < 8; ++e) {
        const float* bb = bias + e * 1024 + h;
        float4 b0 = ((const float4*)bb)[0], b1 = ((const float4*)bb)[1];
        v0.x += gg[e] * b0.x; v0.y += gg[e] * b0.y; v0.z += gg[e] * b0.z; v0.w += gg[e] * b0.w;
        v1.x += gg[e] * b1.x; v1.y += gg[e] * b1.y; v1.z += gg[e] * b1.z; v1.w += gg[e] * b1.w;
    }
    float m[8] = {v0.x, v0.y, v0.z, v0.w, v1.x, v1.y, v1.z, v1.w};
    #pragma unroll
    for (int j = 0; j < 8; ++j) m[j] = m[j] > 0.f ? m[j] : expm1f(m[j]);
    u16* o = At + b * 8192 + h;
    #pragma unroll
    for (int e = 0; e < 8; ++e) {
        u16x8 r;
        #pragma unroll
        for (int j = 0; j < 8; ++j) r[j] = f2bf(gg[e] * m[j]);
        *(u16x8*)(o + e * 1024) = r;
    }
}

// ---------------- launcher ----------------------------------------------------
extern "C" void kernel_launch(void* const* d_in, const int* in_sizes, int n_in,
                              void* d_out, int out_size, void* d_ws, size_t ws_size,
                              hipStream_t stream) {
    const float* X  = (const float*)d_in[0];   // [8192,512]
    const float* W  = (const float*)d_in[1];   // [8192,8]
    const float* W1 = (const float*)d_in[2];   // [8,1024,512]
    const float* b1 = (const float*)d_in[3];   // [8,1024]
    const float* W2 = (const float*)d_in[4];   // [8,1024,1024]
    const float* b2 = (const float*)d_in[5];   // [8,1024]
    const float* W3 = (const float*)d_in[6];   // [8,512,1024]
    const float* b3 = (const float*)d_in[7];   // [8,512]
    float* out = (float*)d_out;

    char* ws = (char*)d_ws;
    u16* W1b  = (u16*)ws;  ws += (size_t)8 * 1024 * 512 * 2;     //  8.4 MB
    u16* W2b  = (u16*)ws;  ws += (size_t)8 * 1024 * 1024 * 2;    // 16.8 MB
    u16* W3b  = (u16*)ws;  ws += (size_t)8 * 512 * 1024 * 2;     //  8.4 MB
    u16* At1  = (u16*)ws;  ws += (size_t)8192 * 4096 * 2;        //   67 MB
    u16* At2  = (u16*)ws;  ws += (size_t)8192 * 8192 * 2;        //  134 MB

    // partial slabs reuse dead regions:
    float* P2 = (float*)At1;   // L2 gemm -> fused reduce2/atilde3 (At1 dead after L1)
    float* P3 = (float*)At1;   // L3 gemm -> L3 reduce (P2 consumed)

    // weight converts
    cvt_f32_bf16<<<4096, 256, 0, stream>>>(W1, W1b, 4194304 / 4);
    cvt_f32_bf16<<<8192, 256, 0, stream>>>(W2, W2b, 8388608 / 4);
    cvt_f32_bf16<<<4096, 256, 0, stream>>>(W3, W3b, 4194304 / 4);

    dim3 blk(256);

    // L1: At1 = gate ⊙ X [8192,4096]; fused S=1 GEMM -> At2 (bias+ELU+8 gated copies)
    make_atilde_f32<<<16384, blk, 0, stream>>>(X, W, At1, 9);
    moe_gemm_l1f<<<512, blk, 0, stream>>>(At1, W1b, W, b1, At2, 1024, 512, 4096, 3, 64);

    // L2: S=2 GEMM over At2; fused reduce+atilde -> At3(=At2)
    moe_gemm_2b<<<256, 512, 0, stream>>>(At2, W2b, P2, 1024, 1024, 8192, 4, 64, 2);
    reduce_atilde2<<<4096, blk, 0, stream>>>(P2, W, b2, At2);

    // L3: S=4 GEMM over At2; reduce -> out (f32)
    moe_gemm_2b<<<256, 512, 0, stream>>>(At2, W3b, P3, 512, 1024, 8192, 4, 32, 1);
    moe_reduce<4, false, false><<<2048, blk, 0, stream>>>(P3, W, b3, (void*)out, 9, 8192 * 512 / 4);
}